// Round 1
// baseline (487.869 us; speedup 1.0000x reference)
//
#include <hip/hip_runtime.h>
#include <math.h>

#define NEG_SLOPE 0.2f
#define EPS_DEN 1e-16f

// ---------------- CSR build ----------------
__global__ void k_count(const int* __restrict__ ei, int E, int Nn, int* counts) {
    int e = blockIdx.x * blockDim.x + threadIdx.x;
    int ET = E + Nn;
    if (e >= ET) return;
    int d = (e < E) ? ei[E + e] : (e - E);
    atomicAdd(&counts[d], 1);
}

__global__ void k_scan(const int* __restrict__ counts, int Nn, int ET, int* __restrict__ row_off) {
    __shared__ int lds[256];
    int t = threadIdx.x;
    int chunk = (Nn + 255) / 256;
    int b0 = t * chunk, b1 = min(Nn, b0 + chunk);
    int s = 0;
    for (int i = b0; i < b1; i++) s += counts[i];
    lds[t] = s;
    __syncthreads();
    if (t == 0) {
        int run = 0;
        for (int i = 0; i < 256; i++) { int v = lds[i]; lds[i] = run; run += v; }
    }
    __syncthreads();
    int run = lds[t];
    for (int i = b0; i < b1; i++) { row_off[i] = run; run += counts[i]; }
    if (t == 0) row_off[Nn] = ET;
}

__global__ void k_scatter(const int* __restrict__ ei, int E, int Nn,
                          const int* __restrict__ row_off, int* cursor, int* __restrict__ col) {
    int e = blockIdx.x * blockDim.x + threadIdx.x;
    int ET = E + Nn;
    if (e >= ET) return;
    int d = (e < E) ? ei[E + e] : (e - E);
    int s = (e < E) ? ei[e] : (e - E);
    int pos = atomicAdd(&cursor[d], 1);
    col[row_off[d] + pos] = s;
}

// ---------------- fp32 tiled GEMM: C[M,N] = A[M,K] @ B[K,N], N%64==0, K%16==0 ----------------
__global__ __launch_bounds__(256) void k_gemm(const float* __restrict__ A, const float* __restrict__ B,
                                              float* __restrict__ C, int M, int N, int K) {
    __shared__ float As[16][64];
    __shared__ float Bs[16][64];
    int tid = threadIdx.x;
    int tx = tid & 15, ty = tid >> 4;
    int bm0 = blockIdx.y * 64, bn0 = blockIdx.x * 64;

    float4 acc[4];
    #pragma unroll
    for (int i = 0; i < 4; i++) acc[i] = make_float4(0.f, 0.f, 0.f, 0.f);

    int arow = tid >> 2, acol = (tid & 3) << 2;
    int brow = tid >> 4, bcol = (tid & 15) << 2;

    for (int k0 = 0; k0 < K; k0 += 16) {
        float4 av = make_float4(0.f, 0.f, 0.f, 0.f);
        int m = bm0 + arow;
        if (m < M) av = *(const float4*)(A + (size_t)m * K + k0 + acol);
        As[acol + 0][arow] = av.x;
        As[acol + 1][arow] = av.y;
        As[acol + 2][arow] = av.z;
        As[acol + 3][arow] = av.w;
        *(float4*)&Bs[brow][bcol] = *(const float4*)(B + (size_t)(k0 + brow) * N + bn0 + bcol);
        __syncthreads();
        #pragma unroll
        for (int k = 0; k < 16; k++) {
            float4 a = *(const float4*)&As[k][ty << 2];
            float4 b = *(const float4*)&Bs[k][tx << 2];
            acc[0].x += a.x * b.x; acc[0].y += a.x * b.y; acc[0].z += a.x * b.z; acc[0].w += a.x * b.w;
            acc[1].x += a.y * b.x; acc[1].y += a.y * b.y; acc[1].z += a.y * b.z; acc[1].w += a.y * b.w;
            acc[2].x += a.z * b.x; acc[2].y += a.z * b.y; acc[2].z += a.z * b.z; acc[2].w += a.z * b.w;
            acc[3].x += a.w * b.x; acc[3].y += a.w * b.y; acc[3].z += a.w * b.z; acc[3].w += a.w * b.w;
        }
        __syncthreads();
    }
    #pragma unroll
    for (int i = 0; i < 4; i++) {
        int m = bm0 + (ty << 2) + i;
        if (m < M) *(float4*)(C + (size_t)m * N + bn0 + (tx << 2)) = acc[i];
    }
}

// ---------------- layer-3 GEMM: N=3, K=512, wave per row ----------------
__global__ __launch_bounds__(256) void k_gemm_n3(const float* __restrict__ A, const float* __restrict__ W,
                                                 float* __restrict__ C3, int M, int K) {
    __shared__ float lw[1536];
    int t = threadIdx.x;
    for (int i = t; i < K * 3; i += 256) lw[i] = W[i];
    __syncthreads();
    int lane = t & 63;
    int n = blockIdx.x * 4 + (t >> 6);
    if (n >= M) return;
    float a0 = 0.f, a1 = 0.f, a2 = 0.f;
    for (int c = lane; c < K; c += 64) {
        float v = A[(size_t)n * K + c];
        a0 += v * lw[c * 3 + 0];
        a1 += v * lw[c * 3 + 1];
        a2 += v * lw[c * 3 + 2];
    }
    #pragma unroll
    for (int off = 32; off > 0; off >>= 1) {
        a0 += __shfl_xor(a0, off);
        a1 += __shfl_xor(a1, off);
        a2 += __shfl_xor(a2, off);
    }
    if (lane == 0) { C3[n * 3 + 0] = a0; C3[n * 3 + 1] = a1; C3[n * 3 + 2] = a2; }
}

// ---------------- attention source/dst scores: wave per (n,h) ----------------
template<int H, int C>
__global__ __launch_bounds__(256) void k_scores(const float* __restrict__ h, const float* __restrict__ a_src,
                                                const float* __restrict__ a_dst, float* __restrict__ ssrc,
                                                float* __restrict__ sdst, int Nn) {
    int lane = threadIdx.x & 63;
    int w = blockIdx.x * (blockDim.x >> 6) + (threadIdx.x >> 6);
    if (w >= Nn * H) return;
    int n = w / H, hh = w - n * H;
    float as = 0.f, ad = 0.f;
    for (int c = lane; c < C; c += 64) {
        float v = h[(size_t)n * (H * C) + hh * C + c];
        as += v * a_src[hh * C + c];
        ad += v * a_dst[hh * C + c];
    }
    #pragma unroll
    for (int off = 32; off > 0; off >>= 1) { as += __shfl_xor(as, off); ad += __shfl_xor(ad, off); }
    if (lane == 0) { ssrc[w] = as; sdst[w] = ad; }
}

// ---------------- segmented softmax over incoming edges: thread per (n,h) ----------------
template<int H>
__global__ void k_edge_soft(const float* __restrict__ ssrc, const float* __restrict__ sdst,
                            const int* __restrict__ col, const int* __restrict__ row_off,
                            float* __restrict__ sc, float* __restrict__ inv, int Nn) {
    int p = blockIdx.x * blockDim.x + threadIdx.x;
    if (p >= Nn * H) return;
    int n = p / H, hh = p - n * H;
    int beg = row_off[n], end = row_off[n + 1];
    float sd = sdst[p];
    float mx = -1e30f;
    for (int j = beg; j < end; j++) {
        float s = ssrc[col[j] * H + hh] + sd;
        s = (s >= 0.f) ? s : NEG_SLOPE * s;
        sc[(size_t)j * H + hh] = s;
        mx = fmaxf(mx, s);
    }
    float den = 0.f;
    for (int j = beg; j < end; j++) {
        float ex = __expf(sc[(size_t)j * H + hh] - mx);
        sc[(size_t)j * H + hh] = ex;
        den += ex;
    }
    inv[p] = 1.f / (den + EPS_DEN);
}

// ---------------- aggregation: block per dst node, D=H*C outputs ----------------
template<int H, int C, bool ELU>
__global__ __launch_bounds__(256) void k_agg(const float* __restrict__ hsrc, const float* __restrict__ sc,
                                             const float* __restrict__ inv, const int* __restrict__ col,
                                             const int* __restrict__ row_off, const float* __restrict__ bias,
                                             float* __restrict__ out) {
    constexpr int D = H * C;
    constexpr int R = D / 256;
    int n = blockIdx.x, t = threadIdx.x;
    int beg = row_off[n], end = row_off[n + 1];
    __shared__ int s_col[32];
    __shared__ float s_ex[32 * H];
    float acc[R];
    #pragma unroll
    for (int r = 0; r < R; r++) acc[r] = 0.f;

    for (int j0 = beg; j0 < end; j0 += 32) {
        int nb = min(32, end - j0);
        __syncthreads();
        if (t < nb) s_col[t] = col[j0 + t];
        if (t < nb * H) s_ex[t] = sc[(size_t)j0 * H + t];
        __syncthreads();
        for (int i = 0; i < nb; i++) {
            const float* hp = hsrc + (size_t)s_col[i] * D;
            float e_cached[ (R + (C/256) > 0) ? 1 : 1 ]; (void)e_cached;
            #pragma unroll
            for (int r = 0; r < R; r++) {
                int idx = t + r * 256;
                acc[r] += s_ex[i * H + (idx / C)] * hp[idx];
            }
        }
    }
    #pragma unroll
    for (int r = 0; r < R; r++) {
        int idx = t + r * 256;
        float v = acc[r] * inv[n * H + idx / C] + bias[idx];
        if (ELU) v = (v > 0.f) ? v : (__expf(v) - 1.f);
        out[(size_t)n * D + idx] = v;
    }
}

// ---------------- layer-3 aggregation + bias + log_softmax ----------------
__global__ void k_agg3_lsm(const float* __restrict__ h3, const float* __restrict__ sc,
                           const float* __restrict__ inv, const int* __restrict__ col,
                           const int* __restrict__ row_off, const float* __restrict__ b3,
                           float* __restrict__ out, int Nn) {
    int n = blockIdx.x * blockDim.x + threadIdx.x;
    if (n >= Nn) return;
    int beg = row_off[n], end = row_off[n + 1];
    float a0 = 0.f, a1 = 0.f, a2 = 0.f;
    for (int j = beg; j < end; j++) {
        int s = col[j];
        float ex = sc[j];
        a0 += ex * h3[s * 3 + 0];
        a1 += ex * h3[s * 3 + 1];
        a2 += ex * h3[s * 3 + 2];
    }
    float iv = inv[n];
    float v0 = a0 * iv + b3[0], v1 = a1 * iv + b3[1], v2 = a2 * iv + b3[2];
    float m = fmaxf(v0, fmaxf(v1, v2));
    float l = logf(__expf(v0 - m) + __expf(v1 - m) + __expf(v2 - m));
    out[n * 3 + 0] = v0 - m - l;
    out[n * 3 + 1] = v1 - m - l;
    out[n * 3 + 2] = v2 - m - l;
}

extern "C" void kernel_launch(void* const* d_in, const int* in_sizes, int n_in,
                              void* d_out, int out_size, void* d_ws, size_t ws_size,
                              hipStream_t stream) {
    (void)n_in; (void)out_size; (void)ws_size;
    const float* x   = (const float*)d_in[0];
    const int*   ei  = (const int*)d_in[1];
    const float* W1  = (const float*)d_in[2];
    const float* as1 = (const float*)d_in[3];
    const float* ad1 = (const float*)d_in[4];
    const float* b1  = (const float*)d_in[5];
    const float* W2  = (const float*)d_in[6];
    const float* as2 = (const float*)d_in[7];
    const float* ad2 = (const float*)d_in[8];
    const float* b2  = (const float*)d_in[9];
    const float* W3  = (const float*)d_in[10];
    const float* as3 = (const float*)d_in[11];
    const float* ad3 = (const float*)d_in[12];
    const float* b3  = (const float*)d_in[13];
    float* out = (float*)d_out;

    const int Nn = in_sizes[0] / 64;   // 10000
    const int E  = in_sizes[1] / 2;    // 160000
    const int ET = E + Nn;

    char* ws = (char*)d_ws;
    size_t off = 0;
    auto alloc = [&](size_t bytes) -> void* {
        void* p = ws + off;
        off = (off + bytes + 255) & ~(size_t)255;
        return p;
    };
    float* hbuf   = (float*)alloc((size_t)Nn * 1024 * 4);
    float* obuf   = (float*)alloc((size_t)Nn * 1024 * 4);
    float* sc     = (float*)alloc((size_t)ET * 8 * 4);
    float* ssrc   = (float*)alloc((size_t)Nn * 8 * 4);
    float* sdst   = (float*)alloc((size_t)Nn * 8 * 4);
    float* inv    = (float*)alloc((size_t)Nn * 8 * 4);
    int*   counts = (int*)alloc((size_t)Nn * 4);
    int*   cursor = (int*)alloc((size_t)Nn * 4);
    int*   row_off= (int*)alloc((size_t)(Nn + 1) * 4);
    int*   col    = (int*)alloc((size_t)ET * 4);

    hipMemsetAsync(counts, 0, (size_t)Nn * 4, stream);
    hipMemsetAsync(cursor, 0, (size_t)Nn * 4, stream);

    int etb = (ET + 255) / 256;
    k_count<<<etb, 256, 0, stream>>>(ei, E, Nn, counts);
    k_scan<<<1, 256, 0, stream>>>(counts, Nn, ET, row_off);
    k_scatter<<<etb, 256, 0, stream>>>(ei, E, Nn, row_off, cursor, col);

    // ---- layer 1: F_IN=64 -> 8x128, concat ----
    {
        dim3 grid(1024 / 64, (Nn + 63) / 64);
        k_gemm<<<grid, 256, 0, stream>>>(x, W1, hbuf, Nn, 1024, 64);
        int nw = Nn * 8;
        k_scores<8, 128><<<(nw + 3) / 4, 256, 0, stream>>>(hbuf, as1, ad1, ssrc, sdst, Nn);
        k_edge_soft<8><<<(nw + 255) / 256, 256, 0, stream>>>(ssrc, sdst, col, row_off, sc, inv, Nn);
        k_agg<8, 128, true><<<Nn, 256, 0, stream>>>(hbuf, sc, inv, col, row_off, b1, obuf);
    }
    // ---- layer 2: 1024 -> 8x64, concat ----
    {
        dim3 grid(512 / 64, (Nn + 63) / 64);
        k_gemm<<<grid, 256, 0, stream>>>(obuf, W2, hbuf, Nn, 512, 1024);
        int nw = Nn * 8;
        k_scores<8, 64><<<(nw + 3) / 4, 256, 0, stream>>>(hbuf, as2, ad2, ssrc, sdst, Nn);
        k_edge_soft<8><<<(nw + 255) / 256, 256, 0, stream>>>(ssrc, sdst, col, row_off, sc, inv, Nn);
        k_agg<8, 64, true><<<Nn, 256, 0, stream>>>(hbuf, sc, inv, col, row_off, b2, obuf);
    }
    // ---- layer 3: 512 -> 1x3, mean + log_softmax ----
    {
        k_gemm_n3<<<(Nn + 3) / 4, 256, 0, stream>>>(obuf, W3, hbuf, Nn, 512);
        k_scores<1, 3><<<(Nn + 3) / 4, 256, 0, stream>>>(hbuf, as3, ad3, ssrc, sdst, Nn);
        k_edge_soft<1><<<(Nn + 255) / 256, 256, 0, stream>>>(ssrc, sdst, col, row_off, sc, inv, Nn);
        k_agg3_lsm<<<(Nn + 255) / 256, 256, 0, stream>>>(hbuf, sc, inv, col, row_off, b3, out, Nn);
    }
}

// Round 2
// 419.539 us; speedup vs baseline: 1.1629x; 1.1629x over previous
//
#include <hip/hip_runtime.h>
#include <math.h>

#define NEG_SLOPE 0.2f
#define EPS_DEN 1e-16f

typedef __attribute__((ext_vector_type(8))) short bf16x8;
typedef __attribute__((ext_vector_type(4))) float f32x4;

__device__ inline void split2(float a, short& hi, short& lo) {
    unsigned u = __float_as_uint(a);
    unsigned uh = (u + 0x8000u) & 0xFFFF0000u;   // RN to bf16
    float fh = __uint_as_float(uh);
    hi = (short)(uh >> 16);
    float r = a - fh;                            // exact (Sterbenz-ish)
    lo = (short)((__float_as_uint(r) + 0x8000u) >> 16);
}

// ---------------- CSR build ----------------
__global__ void k_count(const int* __restrict__ ei, int E, int Nn, int* counts) {
    int e = blockIdx.x * blockDim.x + threadIdx.x;
    int ET = E + Nn;
    if (e >= ET) return;
    int d = (e < E) ? ei[E + e] : (e - E);
    atomicAdd(&counts[d], 1);
}

__global__ void k_scan(const int* __restrict__ counts, int Nn, int ET, int* __restrict__ row_off) {
    __shared__ int lds[256];
    int t = threadIdx.x;
    int chunk = (Nn + 255) / 256;
    int b0 = t * chunk, b1 = min(Nn, b0 + chunk);
    int s = 0;
    for (int i = b0; i < b1; i++) s += counts[i];
    lds[t] = s;
    __syncthreads();
    if (t == 0) {
        int run = 0;
        for (int i = 0; i < 256; i++) { int v = lds[i]; lds[i] = run; run += v; }
    }
    __syncthreads();
    int run = lds[t];
    for (int i = b0; i < b1; i++) { row_off[i] = run; run += counts[i]; }
    if (t == 0) row_off[Nn] = ET;
}

__global__ void k_scatter(const int* __restrict__ ei, int E, int Nn,
                          const int* __restrict__ row_off, int* cursor, int* __restrict__ col) {
    int e = blockIdx.x * blockDim.x + threadIdx.x;
    int ET = E + Nn;
    if (e >= ET) return;
    int d = (e < E) ? ei[E + e] : (e - E);
    int s = (e < E) ? ei[e] : (e - E);
    int pos = atomicAdd(&cursor[d], 1);
    col[row_off[d] + pos] = s;
}

// ---------------- split conversions ----------------
// x [M,K] f32 -> A' [Mp, 2K] bf16  (cols 0..K-1 = hi, K..2K-1 = lo), pad rows zeroed
__global__ void k_split_x(const float* __restrict__ x, short* __restrict__ A,
                          int M, int Mp, int K) {
    int i = blockIdx.x * blockDim.x + threadIdx.x;
    if (i >= Mp * K) return;
    int row = i / K, c = i - row * K;
    float v = (row < M) ? x[(size_t)row * K + c] : 0.f;
    short hi, lo;
    split2(v, hi, lo);
    A[(size_t)row * (2 * K) + c] = hi;
    A[(size_t)row * (2 * K) + K + c] = lo;
}

// W [K,N] f32 -> Bt [N, 3K] bf16: Bt[n][k]=hi, Bt[n][K+k]=hi, Bt[n][2K+k]=lo
// (transposed so GEMM B-fragments are contiguous along K)
__global__ __launch_bounds__(256) void k_split_wt(const float* __restrict__ W,
                                                  short* __restrict__ Bt, int K, int N) {
    __shared__ float s[32][33];
    int k0 = blockIdx.x * 32, n0 = blockIdx.y * 32;
    int tx = threadIdx.x & 31, ty = threadIdx.x >> 5;   // 32x8
    for (int r = ty; r < 32; r += 8) s[r][tx] = W[(size_t)(k0 + r) * N + n0 + tx];
    __syncthreads();
    for (int r = ty; r < 32; r += 8) {
        float v = s[tx][r];          // = W[k0+tx][n0+r]
        short hi, lo;
        split2(v, hi, lo);
        size_t base = (size_t)(n0 + r) * (3 * K) + k0 + tx;
        Bt[base] = hi;
        Bt[base + K] = hi;
        Bt[base + 2 * K] = lo;
    }
}

// ---------------- MFMA bf16 GEMM: C[M,N] = A'[M,2K] x3-term B't[N,3K] ----------------
// 128x128 tile, 4 waves of 64x64, BK=32, global_load_lds staging.
// k index >= Kwrap wraps back to hi slice of A (A' holds [hi|lo], B't holds [hi|hi|lo]).
__global__ __launch_bounds__(256) void k_mfma(const short* __restrict__ A,
                                              const short* __restrict__ B,
                                              float* __restrict__ C,
                                              int M, int N, int Ktot, int Kwrap,
                                              int lda, int ldb) {
    __shared__ short As[128 * 32];
    __shared__ short Bs[128 * 32];
    int t = threadIdx.x;
    int lane = t & 63;
    int wid = t >> 6;
    int bm = blockIdx.y * 128, bn = blockIdx.x * 128;
    int wm = (wid >> 1) * 64, wn = (wid & 1) * 64;
    int fr = lane & 15, kq = lane >> 4;

    f32x4 acc[4][4] = {};

    for (int k0 = 0; k0 < Ktot; k0 += 32) {
        int ka = (k0 < Kwrap) ? k0 : k0 - Kwrap;
        #pragma unroll
        for (int q = 0; q < 2; q++) {
            int v = q * 256 + t;
            int row = v >> 2, ko = (v & 3) << 3;
            const short* sa = A + (size_t)(bm + row) * lda + ka + ko;
            const short* sb = B + (size_t)(bn + row) * ldb + k0 + ko;
            short* da = As + (size_t)(q * 256 + (wid << 6)) * 8;   // wave-uniform base
            short* db = Bs + (size_t)(q * 256 + (wid << 6)) * 8;
            __builtin_amdgcn_global_load_lds((const __attribute__((address_space(1))) void*)sa,
                                             (__attribute__((address_space(3))) void*)da, 16, 0, 0);
            __builtin_amdgcn_global_load_lds((const __attribute__((address_space(1))) void*)sb,
                                             (__attribute__((address_space(3))) void*)db, 16, 0, 0);
        }
        __syncthreads();
        bf16x8 af[4], bfv[4];
        #pragma unroll
        for (int i = 0; i < 4; i++) {
            af[i]  = *(const bf16x8*)(As + (wm + i * 16 + fr) * 32 + kq * 8);
            bfv[i] = *(const bf16x8*)(Bs + (wn + i * 16 + fr) * 32 + kq * 8);
        }
        #pragma unroll
        for (int i = 0; i < 4; i++)
            #pragma unroll
            for (int j = 0; j < 4; j++)
                acc[i][j] = __builtin_amdgcn_mfma_f32_16x16x32_bf16(af[i], bfv[j], acc[i][j], 0, 0, 0);
        __syncthreads();
    }
    #pragma unroll
    for (int i = 0; i < 4; i++) {
        int rbase = bm + wm + i * 16 + kq * 4;
        #pragma unroll
        for (int j = 0; j < 4; j++) {
            int colc = bn + wn + j * 16 + fr;
            #pragma unroll
            for (int rg = 0; rg < 4; rg++) {
                int r = rbase + rg;
                if (r < M) C[(size_t)r * N + colc] = acc[i][j][rg];
            }
        }
    }
}

// ---------------- layer-3 GEMM: N=3, K=512, wave per row ----------------
__global__ __launch_bounds__(256) void k_gemm_n3(const float* __restrict__ A, const float* __restrict__ W,
                                                 float* __restrict__ C3, int M, int K) {
    __shared__ float lw[1536];
    int t = threadIdx.x;
    for (int i = t; i < K * 3; i += 256) lw[i] = W[i];
    __syncthreads();
    int lane = t & 63;
    int n = blockIdx.x * 4 + (t >> 6);
    if (n >= M) return;
    float a0 = 0.f, a1 = 0.f, a2 = 0.f;
    for (int c = lane; c < K; c += 64) {
        float v = A[(size_t)n * K + c];
        a0 += v * lw[c * 3 + 0];
        a1 += v * lw[c * 3 + 1];
        a2 += v * lw[c * 3 + 2];
    }
    #pragma unroll
    for (int off = 32; off > 0; off >>= 1) {
        a0 += __shfl_xor(a0, off);
        a1 += __shfl_xor(a1, off);
        a2 += __shfl_xor(a2, off);
    }
    if (lane == 0) { C3[n * 3 + 0] = a0; C3[n * 3 + 1] = a1; C3[n * 3 + 2] = a2; }
}

// ---------------- attention source/dst scores: wave per (n,h) ----------------
template<int H, int C>
__global__ __launch_bounds__(256) void k_scores(const float* __restrict__ h, const float* __restrict__ a_src,
                                                const float* __restrict__ a_dst, float* __restrict__ ssrc,
                                                float* __restrict__ sdst, int Nn) {
    int lane = threadIdx.x & 63;
    int w = blockIdx.x * (blockDim.x >> 6) + (threadIdx.x >> 6);
    if (w >= Nn * H) return;
    int n = w / H, hh = w - n * H;
    float as = 0.f, ad = 0.f;
    for (int c = lane; c < C; c += 64) {
        float v = h[(size_t)n * (H * C) + hh * C + c];
        as += v * a_src[hh * C + c];
        ad += v * a_dst[hh * C + c];
    }
    #pragma unroll
    for (int off = 32; off > 0; off >>= 1) { as += __shfl_xor(as, off); ad += __shfl_xor(ad, off); }
    if (lane == 0) { ssrc[w] = as; sdst[w] = ad; }
}

// ---------------- segmented softmax over incoming edges: thread per (n,h) ----------------
template<int H>
__global__ void k_edge_soft(const float* __restrict__ ssrc, const float* __restrict__ sdst,
                            const int* __restrict__ col, const int* __restrict__ row_off,
                            float* __restrict__ sc, float* __restrict__ inv, int Nn) {
    int p = blockIdx.x * blockDim.x + threadIdx.x;
    if (p >= Nn * H) return;
    int n = p / H, hh = p - n * H;
    int beg = row_off[n], end = row_off[n + 1];
    float sd = sdst[p];
    float mx = -1e30f;
    for (int j = beg; j < end; j++) {
        float s = ssrc[col[j] * H + hh] + sd;
        s = (s >= 0.f) ? s : NEG_SLOPE * s;
        sc[(size_t)j * H + hh] = s;
        mx = fmaxf(mx, s);
    }
    float den = 0.f;
    for (int j = beg; j < end; j++) {
        float ex = __expf(sc[(size_t)j * H + hh] - mx);
        sc[(size_t)j * H + hh] = ex;
        den += ex;
    }
    inv[p] = 1.f / (den + EPS_DEN);
}

// ---------------- aggregation: block per dst node, D=H*C outputs ----------------
// SPLIT: writes bf16 hi/lo (row stride 2D) for next layer's MFMA A; else fp32.
template<int H, int C, bool ELU, bool SPLIT>
__global__ __launch_bounds__(256) void k_agg(const float* __restrict__ hsrc, const float* __restrict__ sc,
                                             const float* __restrict__ inv, const int* __restrict__ col,
                                             const int* __restrict__ row_off, const float* __restrict__ bias,
                                             float* __restrict__ out, short* __restrict__ osp) {
    constexpr int D = H * C;
    constexpr int R = D / 256;
    int n = blockIdx.x, t = threadIdx.x;
    int beg = row_off[n], end = row_off[n + 1];
    __shared__ int s_col[32];
    __shared__ float s_ex[32 * H];
    float acc[R];
    #pragma unroll
    for (int r = 0; r < R; r++) acc[r] = 0.f;

    for (int j0 = beg; j0 < end; j0 += 32) {
        int nb = min(32, end - j0);
        __syncthreads();
        if (t < nb) s_col[t] = col[j0 + t];
        if (t < nb * H) s_ex[t] = sc[(size_t)j0 * H + t];
        __syncthreads();
        for (int i = 0; i < nb; i++) {
            const float* hp = hsrc + (size_t)s_col[i] * D;
            #pragma unroll
            for (int r = 0; r < R; r++) {
                int idx = t + r * 256;
                acc[r] += s_ex[i * H + (idx / C)] * hp[idx];
            }
        }
    }
    #pragma unroll
    for (int r = 0; r < R; r++) {
        int idx = t + r * 256;
        float v = acc[r] * inv[n * H + idx / C] + bias[idx];
        if (ELU) v = (v > 0.f) ? v : (__expf(v) - 1.f);
        if (SPLIT) {
            short hi, lo;
            split2(v, hi, lo);
            osp[(size_t)n * (2 * D) + idx] = hi;
            osp[(size_t)n * (2 * D) + D + idx] = lo;
        } else {
            out[(size_t)n * D + idx] = v;
        }
    }
}

// ---------------- layer-3 aggregation + bias + log_softmax ----------------
__global__ void k_agg3_lsm(const float* __restrict__ h3, const float* __restrict__ sc,
                           const float* __restrict__ inv, const int* __restrict__ col,
                           const int* __restrict__ row_off, const float* __restrict__ b3,
                           float* __restrict__ out, int Nn) {
    int n = blockIdx.x * blockDim.x + threadIdx.x;
    if (n >= Nn) return;
    int beg = row_off[n], end = row_off[n + 1];
    float a0 = 0.f, a1 = 0.f, a2 = 0.f;
    for (int j = beg; j < end; j++) {
        int s = col[j];
        float ex = sc[j];
        a0 += ex * h3[s * 3 + 0];
        a1 += ex * h3[s * 3 + 1];
        a2 += ex * h3[s * 3 + 2];
    }
    float iv = inv[n];
    float v0 = a0 * iv + b3[0], v1 = a1 * iv + b3[1], v2 = a2 * iv + b3[2];
    float m = fmaxf(v0, fmaxf(v1, v2));
    float l = logf(__expf(v0 - m) + __expf(v1 - m) + __expf(v2 - m));
    out[n * 3 + 0] = v0 - m - l;
    out[n * 3 + 1] = v1 - m - l;
    out[n * 3 + 2] = v2 - m - l;
}

extern "C" void kernel_launch(void* const* d_in, const int* in_sizes, int n_in,
                              void* d_out, int out_size, void* d_ws, size_t ws_size,
                              hipStream_t stream) {
    (void)n_in; (void)out_size; (void)ws_size;
    const float* x   = (const float*)d_in[0];
    const int*   ei  = (const int*)d_in[1];
    const float* W1  = (const float*)d_in[2];
    const float* as1 = (const float*)d_in[3];
    const float* ad1 = (const float*)d_in[4];
    const float* b1  = (const float*)d_in[5];
    const float* W2  = (const float*)d_in[6];
    const float* as2 = (const float*)d_in[7];
    const float* ad2 = (const float*)d_in[8];
    const float* b2  = (const float*)d_in[9];
    const float* W3  = (const float*)d_in[10];
    const float* as3 = (const float*)d_in[11];
    const float* ad3 = (const float*)d_in[12];
    const float* b3  = (const float*)d_in[13];
    float* out = (float*)d_out;

    const int Nn = in_sizes[0] / 64;   // 10000
    const int E  = in_sizes[1] / 2;    // 160000
    const int ET = E + Nn;
    const int Mp = ((Nn + 127) / 128) * 128;   // 10112

    char* ws = (char*)d_ws;
    size_t off = 0;
    auto alloc = [&](size_t bytes) -> void* {
        void* p = ws + off;
        off = (off + bytes + 255) & ~(size_t)255;
        return p;
    };
    float* hbuf = (float*)alloc((size_t)Nn * 1024 * 4);          // h (both layers)
    // union: A2' bf16 [Mp,2048] (layer1 agg out -> layer2 GEMM A), later obuf f32 [Nn,512]
    void*  big  = alloc((size_t)Mp * 2048 * 2);
    short* A2   = (short*)big;
    float* obuf = (float*)big;
    short* A1   = (short*)alloc((size_t)Mp * 128 * 2);
    short* B1t  = (short*)alloc((size_t)1024 * 192 * 2);
    short* B2t  = (short*)alloc((size_t)512 * 3072 * 2);
    float* sc   = (float*)alloc((size_t)ET * 8 * 4);
    float* ssrc = (float*)alloc((size_t)Nn * 8 * 4);
    float* sdst = (float*)alloc((size_t)Nn * 8 * 4);
    float* inv  = (float*)alloc((size_t)Nn * 8 * 4);
    int* counts = (int*)alloc((size_t)Nn * 4);
    int* cursor = (int*)alloc((size_t)Nn * 4);
    int* row_off= (int*)alloc((size_t)(Nn + 1) * 4);
    int* colb   = (int*)alloc((size_t)ET * 4);

    hipMemsetAsync(counts, 0, (size_t)Nn * 4, stream);
    hipMemsetAsync(cursor, 0, (size_t)Nn * 4, stream);

    int etb = (ET + 255) / 256;
    k_count<<<etb, 256, 0, stream>>>(ei, E, Nn, counts);
    k_scan<<<1, 256, 0, stream>>>(counts, Nn, ET, row_off);
    k_scatter<<<etb, 256, 0, stream>>>(ei, E, Nn, row_off, cursor, colb);

    // weight/input splits
    k_split_x<<<(Mp * 64 + 255) / 256, 256, 0, stream>>>(x, A1, Nn, Mp, 64);
    k_split_wt<<<dim3(64 / 32, 1024 / 32), 256, 0, stream>>>(W1, B1t, 64, 1024);
    k_split_wt<<<dim3(1024 / 32, 512 / 32), 256, 0, stream>>>(W2, B2t, 1024, 512);

    // ---- layer 1: 64 -> 8x128 concat ----
    {
        dim3 grid(1024 / 128, Mp / 128);
        k_mfma<<<grid, 256, 0, stream>>>(A1, B1t, hbuf, Nn, 1024, 192, 128, 128, 192);
        int nw = Nn * 8;
        k_scores<8, 128><<<(nw + 3) / 4, 256, 0, stream>>>(hbuf, as1, ad1, ssrc, sdst, Nn);
        k_edge_soft<8><<<(nw + 255) / 256, 256, 0, stream>>>(ssrc, sdst, colb, row_off, sc, inv, Nn);
        k_agg<8, 128, true, true><<<Nn, 256, 0, stream>>>(hbuf, sc, inv, colb, row_off, b1, nullptr, A2);
    }
    // ---- layer 2: 1024 -> 8x64 concat ----
    {
        dim3 grid(512 / 128, Mp / 128);
        k_mfma<<<grid, 256, 0, stream>>>(A2, B2t, hbuf, Nn, 512, 3072, 2048, 2048, 3072);
        int nw = Nn * 8;
        k_scores<8, 64><<<(nw + 3) / 4, 256, 0, stream>>>(hbuf, as2, ad2, ssrc, sdst, Nn);
        k_edge_soft<8><<<(nw + 255) / 256, 256, 0, stream>>>(ssrc, sdst, colb, row_off, sc, inv, Nn);
        k_agg<8, 64, true, false><<<Nn, 256, 0, stream>>>(hbuf, sc, inv, colb, row_off, b2, obuf, nullptr);
    }
    // ---- layer 3: 512 -> 1x3, mean + log_softmax ----
    {
        k_gemm_n3<<<(Nn + 3) / 4, 256, 0, stream>>>(obuf, W3, hbuf, Nn, 512);
        k_scores<1, 3><<<(Nn + 3) / 4, 256, 0, stream>>>(hbuf, as3, ad3, ssrc, sdst, Nn);
        k_edge_soft<1><<<(Nn + 255) / 256, 256, 0, stream>>>(ssrc, sdst, colb, row_off, sc, inv, Nn);
        k_agg3_lsm<<<(Nn + 255) / 256, 256, 0, stream>>>(hbuf, sc, inv, colb, row_off, b3, out, Nn);
    }
}

// Round 3
// 351.036 us; speedup vs baseline: 1.3898x; 1.1951x over previous
//
#include <hip/hip_runtime.h>
#include <math.h>

#define NEG_SLOPE 0.2f
#define EPS_DEN 1e-16f

typedef __attribute__((ext_vector_type(8))) short bf16x8;
typedef __attribute__((ext_vector_type(4))) float f32x4;

__device__ inline void split2(float a, short& hi, short& lo) {
    unsigned u = __float_as_uint(a);
    unsigned uh = (u + 0x8000u) & 0xFFFF0000u;   // RN to bf16
    float fh = __uint_as_float(uh);
    hi = (short)(uh >> 16);
    float r = a - fh;
    lo = (short)((__float_as_uint(r) + 0x8000u) >> 16);
}

__device__ inline unsigned short f2bf(float f) {   // RNE
    unsigned u = __float_as_uint(f);
    return (unsigned short)((u + 0x7FFFu + ((u >> 16) & 1u)) >> 16);
}
__device__ inline float bflo(unsigned u) { return __uint_as_float(u << 16); }
__device__ inline float bfhi(unsigned u) { return __uint_as_float(u & 0xFFFF0000u); }

// ---------------- CSR build ----------------
__global__ void k_count(const int* __restrict__ ei, int E, int Nn, int* counts) {
    int e = blockIdx.x * blockDim.x + threadIdx.x;
    int ET = E + Nn;
    if (e >= ET) return;
    int d = (e < E) ? ei[E + e] : (e - E);
    atomicAdd(&counts[d], 1);
}

__global__ void k_scan(const int* __restrict__ counts, int Nn, int ET, int* __restrict__ row_off) {
    __shared__ int lds[256];
    int t = threadIdx.x;
    int chunk = (Nn + 255) / 256;
    int b0 = t * chunk, b1 = min(Nn, b0 + chunk);
    int s = 0;
    for (int i = b0; i < b1; i++) s += counts[i];
    lds[t] = s;
    __syncthreads();
    if (t == 0) {
        int run = 0;
        for (int i = 0; i < 256; i++) { int v = lds[i]; lds[i] = run; run += v; }
    }
    __syncthreads();
    int run = lds[t];
    for (int i = b0; i < b1; i++) { row_off[i] = run; run += counts[i]; }
    if (t == 0) row_off[Nn] = ET;
}

__global__ void k_scatter(const int* __restrict__ ei, int E, int Nn,
                          const int* __restrict__ row_off, int* cursor, int* __restrict__ col) {
    int e = blockIdx.x * blockDim.x + threadIdx.x;
    int ET = E + Nn;
    if (e >= ET) return;
    int d = (e < E) ? ei[E + e] : (e - E);
    int s = (e < E) ? ei[e] : (e - E);
    int pos = atomicAdd(&cursor[d], 1);
    col[row_off[d] + pos] = s;
}

// ---------------- split conversions ----------------
__global__ void k_split_x(const float* __restrict__ x, short* __restrict__ A,
                          int M, int Mp, int K) {
    int i = blockIdx.x * blockDim.x + threadIdx.x;
    if (i >= Mp * K) return;
    int row = i / K, c = i - row * K;
    float v = (row < M) ? x[(size_t)row * K + c] : 0.f;
    short hi, lo;
    split2(v, hi, lo);
    A[(size_t)row * (2 * K) + c] = hi;
    A[(size_t)row * (2 * K) + K + c] = lo;
}

__global__ __launch_bounds__(256) void k_split_wt(const float* __restrict__ W,
                                                  short* __restrict__ Bt, int K, int N) {
    __shared__ float s[32][33];
    int k0 = blockIdx.x * 32, n0 = blockIdx.y * 32;
    int tx = threadIdx.x & 31, ty = threadIdx.x >> 5;
    for (int r = ty; r < 32; r += 8) s[r][tx] = W[(size_t)(k0 + r) * N + n0 + tx];
    __syncthreads();
    for (int r = ty; r < 32; r += 8) {
        float v = s[tx][r];
        short hi, lo;
        split2(v, hi, lo);
        size_t base = (size_t)(n0 + r) * (3 * K) + k0 + tx;
        Bt[base] = hi;
        Bt[base + K] = hi;
        Bt[base + 2 * K] = lo;
    }
}

// ---------------- MFMA bf16 GEMM, bf16 output ----------------
__global__ __launch_bounds__(256) void k_mfma(const short* __restrict__ A,
                                              const short* __restrict__ B,
                                              unsigned short* __restrict__ C,
                                              int M, int N, int Ktot, int Kwrap,
                                              int lda, int ldb) {
    __shared__ short As[128 * 32];
    __shared__ short Bs[128 * 32];
    int t = threadIdx.x;
    int lane = t & 63;
    int wid = t >> 6;
    int bm = blockIdx.y * 128, bn = blockIdx.x * 128;
    int wm = (wid >> 1) * 64, wn = (wid & 1) * 64;
    int fr = lane & 15, kq = lane >> 4;

    f32x4 acc[4][4] = {};

    for (int k0 = 0; k0 < Ktot; k0 += 32) {
        int ka = (k0 < Kwrap) ? k0 : k0 - Kwrap;
        #pragma unroll
        for (int q = 0; q < 2; q++) {
            int v = q * 256 + t;
            int row = v >> 2, ko = (v & 3) << 3;
            const short* sa = A + (size_t)(bm + row) * lda + ka + ko;
            const short* sb = B + (size_t)(bn + row) * ldb + k0 + ko;
            short* da = As + (size_t)(q * 256 + (wid << 6)) * 8;
            short* db = Bs + (size_t)(q * 256 + (wid << 6)) * 8;
            __builtin_amdgcn_global_load_lds((const __attribute__((address_space(1))) void*)sa,
                                             (__attribute__((address_space(3))) void*)da, 16, 0, 0);
            __builtin_amdgcn_global_load_lds((const __attribute__((address_space(1))) void*)sb,
                                             (__attribute__((address_space(3))) void*)db, 16, 0, 0);
        }
        __syncthreads();
        bf16x8 af[4], bfv[4];
        #pragma unroll
        for (int i = 0; i < 4; i++) {
            af[i]  = *(const bf16x8*)(As + (wm + i * 16 + fr) * 32 + kq * 8);
            bfv[i] = *(const bf16x8*)(Bs + (wn + i * 16 + fr) * 32 + kq * 8);
        }
        #pragma unroll
        for (int i = 0; i < 4; i++)
            #pragma unroll
            for (int j = 0; j < 4; j++)
                acc[i][j] = __builtin_amdgcn_mfma_f32_16x16x32_bf16(af[i], bfv[j], acc[i][j], 0, 0, 0);
        __syncthreads();
    }
    #pragma unroll
    for (int i = 0; i < 4; i++) {
        int rbase = bm + wm + i * 16 + kq * 4;
        #pragma unroll
        for (int j = 0; j < 4; j++) {
            int colc = bn + wn + j * 16 + fr;
            #pragma unroll
            for (int rg = 0; rg < 4; rg++) {
                int r = rbase + rg;
                if (r < M) C[(size_t)r * N + colc] = f2bf(acc[i][j][rg]);
            }
        }
    }
}

// ---------------- layer-3 GEMM: N=3, K=512, wave per row ----------------
__global__ __launch_bounds__(256) void k_gemm_n3(const float* __restrict__ A, const float* __restrict__ W,
                                                 float* __restrict__ C3, int M, int K) {
    __shared__ float lw[1536];
    int t = threadIdx.x;
    for (int i = t; i < K * 3; i += 256) lw[i] = W[i];
    __syncthreads();
    int lane = t & 63;
    int n = blockIdx.x * 4 + (t >> 6);
    if (n >= M) return;
    float a0 = 0.f, a1 = 0.f, a2 = 0.f;
    for (int c = lane; c < K; c += 64) {
        float v = A[(size_t)n * K + c];
        a0 += v * lw[c * 3 + 0];
        a1 += v * lw[c * 3 + 1];
        a2 += v * lw[c * 3 + 2];
    }
    #pragma unroll
    for (int off = 32; off > 0; off >>= 1) {
        a0 += __shfl_xor(a0, off);
        a1 += __shfl_xor(a1, off);
        a2 += __shfl_xor(a2, off);
    }
    if (lane == 0) { C3[n * 3 + 0] = a0; C3[n * 3 + 1] = a1; C3[n * 3 + 2] = a2; }
}

// ---------------- scores from bf16 h: wave per (n,h) ----------------
template<int H, int C>
__global__ __launch_bounds__(256) void k_scores_bf(const unsigned short* __restrict__ h,
                                                   const float* __restrict__ a_src,
                                                   const float* __restrict__ a_dst,
                                                   float* __restrict__ ssrc,
                                                   float* __restrict__ sdst, int Nn) {
    int lane = threadIdx.x & 63;
    int w = blockIdx.x * (blockDim.x >> 6) + (threadIdx.x >> 6);
    if (w >= Nn * H) return;
    int n = w / H, hh = w - n * H;
    float as = 0.f, ad = 0.f;
    for (int c = lane; c < C; c += 64) {
        float v = bflo(h[(size_t)n * (H * C) + hh * C + c]);
        as += v * a_src[hh * C + c];
        ad += v * a_dst[hh * C + c];
    }
    #pragma unroll
    for (int off = 32; off > 0; off >>= 1) { as += __shfl_xor(as, off); ad += __shfl_xor(ad, off); }
    if (lane == 0) { ssrc[w] = as; sdst[w] = ad; }
}

// fp32 variant for layer 3
template<int H, int C>
__global__ __launch_bounds__(256) void k_scores(const float* __restrict__ h, const float* __restrict__ a_src,
                                                const float* __restrict__ a_dst, float* __restrict__ ssrc,
                                                float* __restrict__ sdst, int Nn) {
    int lane = threadIdx.x & 63;
    int w = blockIdx.x * (blockDim.x >> 6) + (threadIdx.x >> 6);
    if (w >= Nn * H) return;
    int n = w / H, hh = w - n * H;
    float as = 0.f, ad = 0.f;
    for (int c = lane; c < C; c += 64) {
        float v = h[(size_t)n * (H * C) + hh * C + c];
        as += v * a_src[hh * C + c];
        ad += v * a_dst[hh * C + c];
    }
    #pragma unroll
    for (int off = 32; off > 0; off >>= 1) { as += __shfl_xor(as, off); ad += __shfl_xor(ad, off); }
    if (lane == 0) { ssrc[w] = as; sdst[w] = ad; }
}

// ---------------- segmented softmax: thread per (n,h) ----------------
template<int H>
__global__ void k_edge_soft(const float* __restrict__ ssrc, const float* __restrict__ sdst,
                            const int* __restrict__ col, const int* __restrict__ row_off,
                            float* __restrict__ sc, float* __restrict__ inv, int Nn) {
    int p = blockIdx.x * blockDim.x + threadIdx.x;
    if (p >= Nn * H) return;
    int n = p / H, hh = p - n * H;
    int beg = row_off[n], end = row_off[n + 1];
    float sd = sdst[p];
    float mx = -1e30f;
    for (int j = beg; j < end; j++) {
        float s = ssrc[col[j] * H + hh] + sd;
        s = (s >= 0.f) ? s : NEG_SLOPE * s;
        sc[(size_t)j * H + hh] = s;
        mx = fmaxf(mx, s);
    }
    float den = 0.f;
    for (int j = beg; j < end; j++) {
        float ex = __expf(sc[(size_t)j * H + hh] - mx);
        sc[(size_t)j * H + hh] = ex;
        den += ex;
    }
    inv[p] = 1.f / (den + EPS_DEN);
}

// ---------------- aggregation from bf16 h: block per dst node ----------------
template<int H, int C, bool ELU, bool SPLIT>
__global__ __launch_bounds__(256) void k_agg_bf(const unsigned short* __restrict__ hsrc,
                                                const float* __restrict__ sc,
                                                const float* __restrict__ inv, const int* __restrict__ col,
                                                const int* __restrict__ row_off, const float* __restrict__ bias,
                                                float* __restrict__ out, short* __restrict__ osp) {
    constexpr int D = H * C;
    constexpr int VEC = D / 256;   // 4 (D=1024) or 2 (D=512)
    int n = blockIdx.x, t = threadIdx.x;
    int head = (VEC * t) / C;      // constant per thread (VEC divides C)
    int beg = row_off[n], end = row_off[n + 1];
    __shared__ int s_col[32];
    __shared__ float s_ex[32 * H];
    float acc[VEC];
    #pragma unroll
    for (int v = 0; v < VEC; v++) acc[v] = 0.f;

    for (int j0 = beg; j0 < end; j0 += 32) {
        int nb = min(32, end - j0);
        __syncthreads();
        if (t < nb) s_col[t] = col[j0 + t];
        if (t < nb * H) s_ex[t] = sc[(size_t)j0 * H + t];
        __syncthreads();
        for (int i = 0; i < nb; i++) {
            const unsigned short* hp = hsrc + (size_t)s_col[i] * D + VEC * t;
            float a = s_ex[i * H + head];
            if (VEC == 4) {
                uint2 u = *(const uint2*)hp;
                acc[0] += a * bflo(u.x);
                acc[1] += a * bfhi(u.x);
                acc[2] += a * bflo(u.y);
                acc[3] += a * bfhi(u.y);
            } else {
                unsigned u = *(const unsigned*)hp;
                acc[0] += a * bflo(u);
                acc[1] += a * bfhi(u);
            }
        }
    }
    float iv = inv[n * H + head];
    #pragma unroll
    for (int v = 0; v < VEC; v++) {
        int idx = VEC * t + v;
        float val = acc[v] * iv + bias[idx];
        if (ELU) val = (val > 0.f) ? val : (__expf(val) - 1.f);
        if (SPLIT) {
            short hi, lo;
            split2(val, hi, lo);
            osp[(size_t)n * (2 * D) + idx] = hi;
            osp[(size_t)n * (2 * D) + D + idx] = lo;
        } else {
            out[(size_t)n * D + idx] = val;
        }
    }
}

// ---------------- layer-3 aggregation + bias + log_softmax ----------------
__global__ void k_agg3_lsm(const float* __restrict__ h3, const float* __restrict__ sc,
                           const float* __restrict__ inv, const int* __restrict__ col,
                           const int* __restrict__ row_off, const float* __restrict__ b3,
                           float* __restrict__ out, int Nn) {
    int n = blockIdx.x * blockDim.x + threadIdx.x;
    if (n >= Nn) return;
    int beg = row_off[n], end = row_off[n + 1];
    float a0 = 0.f, a1 = 0.f, a2 = 0.f;
    for (int j = beg; j < end; j++) {
        int s = col[j];
        float ex = sc[j];
        a0 += ex * h3[s * 3 + 0];
        a1 += ex * h3[s * 3 + 1];
        a2 += ex * h3[s * 3 + 2];
    }
    float iv = inv[n];
    float v0 = a0 * iv + b3[0], v1 = a1 * iv + b3[1], v2 = a2 * iv + b3[2];
    float m = fmaxf(v0, fmaxf(v1, v2));
    float l = logf(__expf(v0 - m) + __expf(v1 - m) + __expf(v2 - m));
    out[n * 3 + 0] = v0 - m - l;
    out[n * 3 + 1] = v1 - m - l;
    out[n * 3 + 2] = v2 - m - l;
}

extern "C" void kernel_launch(void* const* d_in, const int* in_sizes, int n_in,
                              void* d_out, int out_size, void* d_ws, size_t ws_size,
                              hipStream_t stream) {
    (void)n_in; (void)out_size; (void)ws_size;
    const float* x   = (const float*)d_in[0];
    const int*   ei  = (const int*)d_in[1];
    const float* W1  = (const float*)d_in[2];
    const float* as1 = (const float*)d_in[3];
    const float* ad1 = (const float*)d_in[4];
    const float* b1  = (const float*)d_in[5];
    const float* W2  = (const float*)d_in[6];
    const float* as2 = (const float*)d_in[7];
    const float* ad2 = (const float*)d_in[8];
    const float* b2  = (const float*)d_in[9];
    const float* W3  = (const float*)d_in[10];
    const float* as3 = (const float*)d_in[11];
    const float* ad3 = (const float*)d_in[12];
    const float* b3  = (const float*)d_in[13];
    float* out = (float*)d_out;

    const int Nn = in_sizes[0] / 64;   // 10000
    const int E  = in_sizes[1] / 2;    // 160000
    const int ET = E + Nn;
    const int Mp = ((Nn + 127) / 128) * 128;   // 10112

    char* ws = (char*)d_ws;
    size_t off = 0;
    auto alloc = [&](size_t bytes) -> void* {
        void* p = ws + off;
        off = (off + bytes + 255) & ~(size_t)255;
        return p;
    };
    unsigned short* hbuf = (unsigned short*)alloc((size_t)Mp * 1024 * 2);  // bf16 h (both layers)
    // union: A2' bf16 [Mp,2048] (layer1 agg out), later obuf f32 [Nn,512]
    void*  big  = alloc((size_t)Mp * 2048 * 2);
    short* A2   = (short*)big;
    float* obuf = (float*)big;
    float* h3   = (float*)alloc((size_t)Nn * 3 * 4);
    short* A1   = (short*)alloc((size_t)Mp * 128 * 2);
    short* B1t  = (short*)alloc((size_t)1024 * 192 * 2);
    short* B2t  = (short*)alloc((size_t)512 * 3072 * 2);
    float* sc   = (float*)alloc((size_t)ET * 8 * 4);
    float* ssrc = (float*)alloc((size_t)Nn * 8 * 4);
    float* sdst = (float*)alloc((size_t)Nn * 8 * 4);
    float* inv  = (float*)alloc((size_t)Nn * 8 * 4);
    int* counts = (int*)alloc((size_t)Nn * 4);
    int* cursor = (int*)alloc((size_t)Nn * 4);
    int* row_off= (int*)alloc((size_t)(Nn + 1) * 4);
    int* colb   = (int*)alloc((size_t)ET * 4);

    hipMemsetAsync(counts, 0, (size_t)Nn * 4, stream);
    hipMemsetAsync(cursor, 0, (size_t)Nn * 4, stream);

    int etb = (ET + 255) / 256;
    k_count<<<etb, 256, 0, stream>>>(ei, E, Nn, counts);
    k_scan<<<1, 256, 0, stream>>>(counts, Nn, ET, row_off);
    k_scatter<<<etb, 256, 0, stream>>>(ei, E, Nn, row_off, cursor, colb);

    k_split_x<<<(Mp * 64 + 255) / 256, 256, 0, stream>>>(x, A1, Nn, Mp, 64);
    k_split_wt<<<dim3(64 / 32, 1024 / 32), 256, 0, stream>>>(W1, B1t, 64, 1024);
    k_split_wt<<<dim3(1024 / 32, 512 / 32), 256, 0, stream>>>(W2, B2t, 1024, 512);

    // ---- layer 1: 64 -> 8x128 concat ----
    {
        dim3 grid(1024 / 128, Mp / 128);
        k_mfma<<<grid, 256, 0, stream>>>(A1, B1t, hbuf, Nn, 1024, 192, 128, 128, 192);
        int nw = Nn * 8;
        k_scores_bf<8, 128><<<(nw + 3) / 4, 256, 0, stream>>>(hbuf, as1, ad1, ssrc, sdst, Nn);
        k_edge_soft<8><<<(nw + 255) / 256, 256, 0, stream>>>(ssrc, sdst, colb, row_off, sc, inv, Nn);
        k_agg_bf<8, 128, true, true><<<Nn, 256, 0, stream>>>(hbuf, sc, inv, colb, row_off, b1, nullptr, A2);
    }
    // ---- layer 2: 1024 -> 8x64 concat ----
    {
        dim3 grid(512 / 128, Mp / 128);
        k_mfma<<<grid, 256, 0, stream>>>(A2, B2t, hbuf, Nn, 512, 3072, 2048, 2048, 3072);
        int nw = Nn * 8;
        k_scores_bf<8, 64><<<(nw + 3) / 4, 256, 0, stream>>>(hbuf, as2, ad2, ssrc, sdst, Nn);
        k_edge_soft<8><<<(nw + 255) / 256, 256, 0, stream>>>(ssrc, sdst, colb, row_off, sc, inv, Nn);
        k_agg_bf<8, 64, true, false><<<Nn, 256, 0, stream>>>(hbuf, sc, inv, colb, row_off, b2, obuf, nullptr);
    }
    // ---- layer 3: 512 -> 1x3, mean + log_softmax ----
    {
        k_gemm_n3<<<(Nn + 3) / 4, 256, 0, stream>>>(obuf, W3, h3, Nn, 512);
        k_scores<1, 3><<<(Nn + 3) / 4, 256, 0, stream>>>(h3, as3, ad3, ssrc, sdst, Nn);
        k_edge_soft<1><<<(Nn + 255) / 256, 256, 0, stream>>>(ssrc, sdst, colb, row_off, sc, inv, Nn);
        k_agg3_lsm<<<(Nn + 255) / 256, 256, 0, stream>>>(h3, sc, inv, colb, row_off, b3, out, Nn);
    }
}

// Round 4
// 321.113 us; speedup vs baseline: 1.5193x; 1.0932x over previous
//
#include <hip/hip_runtime.h>
#include <math.h>

#define NEG_SLOPE 0.2f
#define EPS_DEN 1e-16f

typedef __attribute__((ext_vector_type(8))) short bf16x8;
typedef __attribute__((ext_vector_type(4))) float f32x4;

__device__ inline void split2(float a, short& hi, short& lo) {
    unsigned u = __float_as_uint(a);
    unsigned uh = (u + 0x8000u) & 0xFFFF0000u;   // RN to bf16
    float fh = __uint_as_float(uh);
    hi = (short)(uh >> 16);
    float r = a - fh;
    lo = (short)((__float_as_uint(r) + 0x8000u) >> 16);
}

__device__ inline unsigned short f2bf(float f) {   // RNE
    unsigned u = __float_as_uint(f);
    return (unsigned short)((u + 0x7FFFu + ((u >> 16) & 1u)) >> 16);
}
__device__ inline float bflo(unsigned u) { return __uint_as_float(u << 16); }
__device__ inline float bfhi(unsigned u) { return __uint_as_float(u & 0xFFFF0000u); }

// ---------------- CSR build ----------------
__global__ void k_count(const int* __restrict__ ei, int E, int Nn, int* counts) {
    int e = blockIdx.x * blockDim.x + threadIdx.x;
    int ET = E + Nn;
    if (e >= ET) return;
    int d = (e < E) ? ei[E + e] : (e - E);
    atomicAdd(&counts[d], 1);
}

__global__ void k_scan(const int* __restrict__ counts, int Nn, int ET, int* __restrict__ row_off) {
    __shared__ int lds[256];
    int t = threadIdx.x;
    int chunk = (Nn + 255) / 256;
    int b0 = t * chunk, b1 = min(Nn, b0 + chunk);
    int s = 0;
    for (int i = b0; i < b1; i++) s += counts[i];
    lds[t] = s;
    __syncthreads();
    if (t == 0) {
        int run = 0;
        for (int i = 0; i < 256; i++) { int v = lds[i]; lds[i] = run; run += v; }
    }
    __syncthreads();
    int run = lds[t];
    for (int i = b0; i < b1; i++) { row_off[i] = run; run += counts[i]; }
    if (t == 0) row_off[Nn] = ET;
}

__global__ void k_scatter(const int* __restrict__ ei, int E, int Nn,
                          const int* __restrict__ row_off, int* cursor, int* __restrict__ col) {
    int e = blockIdx.x * blockDim.x + threadIdx.x;
    int ET = E + Nn;
    if (e >= ET) return;
    int d = (e < E) ? ei[E + e] : (e - E);
    int s = (e < E) ? ei[e] : (e - E);
    int pos = atomicAdd(&cursor[d], 1);
    col[row_off[d] + pos] = s;
}

// ---------------- split conversions ----------------
__global__ void k_split_x(const float* __restrict__ x, short* __restrict__ A,
                          int M, int Mp, int K) {
    int i = blockIdx.x * blockDim.x + threadIdx.x;
    if (i >= Mp * K) return;
    int row = i / K, c = i - row * K;
    float v = (row < M) ? x[(size_t)row * K + c] : 0.f;
    short hi, lo;
    split2(v, hi, lo);
    A[(size_t)row * (2 * K) + c] = hi;
    A[(size_t)row * (2 * K) + K + c] = lo;
}

__global__ __launch_bounds__(256) void k_split_wt(const float* __restrict__ W,
                                                  short* __restrict__ Bt, int K, int N) {
    __shared__ float s[32][33];
    int k0 = blockIdx.x * 32, n0 = blockIdx.y * 32;
    int tx = threadIdx.x & 31, ty = threadIdx.x >> 5;
    for (int r = ty; r < 32; r += 8) s[r][tx] = W[(size_t)(k0 + r) * N + n0 + tx];
    __syncthreads();
    for (int r = ty; r < 32; r += 8) {
        float v = s[tx][r];
        short hi, lo;
        split2(v, hi, lo);
        size_t base = (size_t)(n0 + r) * (3 * K) + k0 + tx;
        Bt[base] = hi;
        Bt[base + K] = hi;
        Bt[base + 2 * K] = lo;
    }
}

// ---------------- MFMA bf16 GEMM, 64x64 tile, XCD-grouped, swizzled LDS ----------------
// C[M,N](bf16) = A'[M,2K?] x B't[N,3K?]; k>=Kwrap wraps A back to hi slice.
// grid: 1-D, nb = (N/64)*(Mp/64) blocks; logical L = chunked(bid) so blocks
// sharing an A-row-panel run on one XCD.
__global__ __launch_bounds__(256) void k_mfma64(const short* __restrict__ A,
                                                const short* __restrict__ B,
                                                unsigned short* __restrict__ C,
                                                int M, int N, int Ktot, int Kwrap,
                                                int lda, int ldb) {
    __shared__ short As[64 * 32];
    __shared__ short Bs[64 * 32];
    int t = threadIdx.x;
    int lane = t & 63;
    int wid = t >> 6;

    int nbx = N >> 6;
    int nb = gridDim.x;
    int q = nb >> 3, r = nb & 7;
    int xcd = blockIdx.x & 7, pos = blockIdx.x >> 3;
    int L = (xcd < r ? xcd * (q + 1) : r * (q + 1) + (xcd - r) * q) + pos;
    int bn = (L % nbx) * 64;
    int bm = (L / nbx) * 64;

    int wm = (wid >> 1) * 32, wn = (wid & 1) * 32;
    int fr = lane & 15, kq = lane >> 4;

    // staging decomposition: thread t covers row = t>>2, slot = t&3 (8 shorts)
    int srow = t >> 2, sslot = t & 3;
    int sko = ((sslot ^ ((srow >> 1) & 3)) << 3);   // pre-swizzled source k-offset

    f32x4 acc[2][2] = {};

    for (int k0 = 0; k0 < Ktot; k0 += 32) {
        int ka = (k0 < Kwrap) ? k0 : k0 - Kwrap;
        {
            const short* sa = A + (size_t)(bm + srow) * lda + ka + sko;
            const short* sb = B + (size_t)(bn + srow) * ldb + k0 + sko;
            short* da = As + (size_t)(wid << 6) * 8;   // wave-uniform base, lane*16B auto
            short* db = Bs + (size_t)(wid << 6) * 8;
            __builtin_amdgcn_global_load_lds((const __attribute__((address_space(1))) void*)sa,
                                             (__attribute__((address_space(3))) void*)da, 16, 0, 0);
            __builtin_amdgcn_global_load_lds((const __attribute__((address_space(1))) void*)sb,
                                             (__attribute__((address_space(3))) void*)db, 16, 0, 0);
        }
        __syncthreads();
        bf16x8 af[2], bfv[2];
        #pragma unroll
        for (int i = 0; i < 2; i++) {
            int rowa = wm + i * 16 + fr;
            int rowb = wn + i * 16 + fr;
            af[i]  = *(const bf16x8*)(As + rowa * 32 + ((kq ^ ((rowa >> 1) & 3)) << 3));
            bfv[i] = *(const bf16x8*)(Bs + rowb * 32 + ((kq ^ ((rowb >> 1) & 3)) << 3));
        }
        #pragma unroll
        for (int i = 0; i < 2; i++)
            #pragma unroll
            for (int j = 0; j < 2; j++)
                acc[i][j] = __builtin_amdgcn_mfma_f32_16x16x32_bf16(af[i], bfv[j], acc[i][j], 0, 0, 0);
        __syncthreads();
    }
    #pragma unroll
    for (int i = 0; i < 2; i++) {
        int rbase = bm + wm + i * 16 + kq * 4;
        #pragma unroll
        for (int j = 0; j < 2; j++) {
            int colc = bn + wn + j * 16 + fr;
            #pragma unroll
            for (int rg = 0; rg < 4; rg++) {
                int rr = rbase + rg;
                if (rr < M) C[(size_t)rr * N + colc] = f2bf(acc[i][j][rg]);
            }
        }
    }
}

// ---------------- layer-3 GEMM: N=3, K=512, wave per row ----------------
__global__ __launch_bounds__(256) void k_gemm_n3(const float* __restrict__ A, const float* __restrict__ W,
                                                 float* __restrict__ C3, int M, int K) {
    __shared__ float lw[1536];
    int t = threadIdx.x;
    for (int i = t; i < K * 3; i += 256) lw[i] = W[i];
    __syncthreads();
    int lane = t & 63;
    int n = blockIdx.x * 4 + (t >> 6);
    if (n >= M) return;
    float a0 = 0.f, a1 = 0.f, a2 = 0.f;
    for (int c = lane; c < K; c += 64) {
        float v = A[(size_t)n * K + c];
        a0 += v * lw[c * 3 + 0];
        a1 += v * lw[c * 3 + 1];
        a2 += v * lw[c * 3 + 2];
    }
    #pragma unroll
    for (int off = 32; off > 0; off >>= 1) {
        a0 += __shfl_xor(a0, off);
        a1 += __shfl_xor(a1, off);
        a2 += __shfl_xor(a2, off);
    }
    if (lane == 0) { C3[n * 3 + 0] = a0; C3[n * 3 + 1] = a1; C3[n * 3 + 2] = a2; }
}

// ---------------- scores from bf16 h: wave per (n,h) ----------------
template<int H, int C>
__global__ __launch_bounds__(256) void k_scores_bf(const unsigned short* __restrict__ h,
                                                   const float* __restrict__ a_src,
                                                   const float* __restrict__ a_dst,
                                                   float* __restrict__ ssrc,
                                                   float* __restrict__ sdst, int Nn) {
    int lane = threadIdx.x & 63;
    int w = blockIdx.x * (blockDim.x >> 6) + (threadIdx.x >> 6);
    if (w >= Nn * H) return;
    int n = w / H, hh = w - n * H;
    float as = 0.f, ad = 0.f;
    for (int c = lane; c < C; c += 64) {
        float v = bflo(h[(size_t)n * (H * C) + hh * C + c]);
        as += v * a_src[hh * C + c];
        ad += v * a_dst[hh * C + c];
    }
    #pragma unroll
    for (int off = 32; off > 0; off >>= 1) { as += __shfl_xor(as, off); ad += __shfl_xor(ad, off); }
    if (lane == 0) { ssrc[w] = as; sdst[w] = ad; }
}

template<int H, int C>
__global__ __launch_bounds__(256) void k_scores(const float* __restrict__ h, const float* __restrict__ a_src,
                                                const float* __restrict__ a_dst, float* __restrict__ ssrc,
                                                float* __restrict__ sdst, int Nn) {
    int lane = threadIdx.x & 63;
    int w = blockIdx.x * (blockDim.x >> 6) + (threadIdx.x >> 6);
    if (w >= Nn * H) return;
    int n = w / H, hh = w - n * H;
    float as = 0.f, ad = 0.f;
    for (int c = lane; c < C; c += 64) {
        float v = h[(size_t)n * (H * C) + hh * C + c];
        as += v * a_src[hh * C + c];
        ad += v * a_dst[hh * C + c];
    }
    #pragma unroll
    for (int off = 32; off > 0; off >>= 1) { as += __shfl_xor(as, off); ad += __shfl_xor(ad, off); }
    if (lane == 0) { ssrc[w] = as; sdst[w] = ad; }
}

// ---------------- segmented softmax: thread per (n,h) ----------------
template<int H>
__global__ void k_edge_soft(const float* __restrict__ ssrc, const float* __restrict__ sdst,
                            const int* __restrict__ col, const int* __restrict__ row_off,
                            float* __restrict__ sc, float* __restrict__ inv, int Nn) {
    int p = blockIdx.x * blockDim.x + threadIdx.x;
    if (p >= Nn * H) return;
    int n = p / H, hh = p - n * H;
    int beg = row_off[n], end = row_off[n + 1];
    float sd = sdst[p];
    float mx = -1e30f;
    for (int j = beg; j < end; j++) {
        float s = ssrc[col[j] * H + hh] + sd;
        s = (s >= 0.f) ? s : NEG_SLOPE * s;
        sc[(size_t)j * H + hh] = s;
        mx = fmaxf(mx, s);
    }
    float den = 0.f;
    for (int j = beg; j < end; j++) {
        float ex = __expf(sc[(size_t)j * H + hh] - mx);
        sc[(size_t)j * H + hh] = ex;
        den += ex;
    }
    inv[p] = 1.f / (den + EPS_DEN);
}

// ---------------- aggregation from bf16 h: block per dst node ----------------
template<int H, int C, bool ELU, bool SPLIT>
__global__ __launch_bounds__(256) void k_agg_bf(const unsigned short* __restrict__ hsrc,
                                                const float* __restrict__ sc,
                                                const float* __restrict__ inv, const int* __restrict__ col,
                                                const int* __restrict__ row_off, const float* __restrict__ bias,
                                                float* __restrict__ out, short* __restrict__ osp) {
    constexpr int D = H * C;
    constexpr int VEC = D / 256;
    int n = blockIdx.x, t = threadIdx.x;
    int head = (VEC * t) / C;
    int beg = row_off[n], end = row_off[n + 1];
    __shared__ int s_col[32];
    __shared__ float s_ex[32 * H];
    float acc[VEC];
    #pragma unroll
    for (int v = 0; v < VEC; v++) acc[v] = 0.f;

    for (int j0 = beg; j0 < end; j0 += 32) {
        int nb = min(32, end - j0);
        __syncthreads();
        if (t < nb) s_col[t] = col[j0 + t];
        if (t < nb * H) s_ex[t] = sc[(size_t)j0 * H + t];
        __syncthreads();
        for (int i = 0; i < nb; i++) {
            const unsigned short* hp = hsrc + (size_t)s_col[i] * D + VEC * t;
            float a = s_ex[i * H + head];
            if (VEC == 4) {
                uint2 u = *(const uint2*)hp;
                acc[0] += a * bflo(u.x);
                acc[1] += a * bfhi(u.x);
                acc[2] += a * bflo(u.y);
                acc[3] += a * bfhi(u.y);
            } else {
                unsigned u = *(const unsigned*)hp;
                acc[0] += a * bflo(u);
                acc[1] += a * bfhi(u);
            }
        }
    }
    float iv = inv[n * H + head];
    #pragma unroll
    for (int v = 0; v < VEC; v++) {
        int idx = VEC * t + v;
        float val = acc[v] * iv + bias[idx];
        if (ELU) val = (val > 0.f) ? val : (__expf(val) - 1.f);
        if (SPLIT) {
            short hi, lo;
            split2(val, hi, lo);
            osp[(size_t)n * (2 * D) + idx] = hi;
            osp[(size_t)n * (2 * D) + D + idx] = lo;
        } else {
            out[(size_t)n * D + idx] = val;
        }
    }
}

// ---------------- layer-3 aggregation + bias + log_softmax ----------------
__global__ void k_agg3_lsm(const float* __restrict__ h3, const float* __restrict__ sc,
                           const float* __restrict__ inv, const int* __restrict__ col,
                           const int* __restrict__ row_off, const float* __restrict__ b3,
                           float* __restrict__ out, int Nn) {
    int n = blockIdx.x * blockDim.x + threadIdx.x;
    if (n >= Nn) return;
    int beg = row_off[n], end = row_off[n + 1];
    float a0 = 0.f, a1 = 0.f, a2 = 0.f;
    for (int j = beg; j < end; j++) {
        int s = col[j];
        float ex = sc[j];
        a0 += ex * h3[s * 3 + 0];
        a1 += ex * h3[s * 3 + 1];
        a2 += ex * h3[s * 3 + 2];
    }
    float iv = inv[n];
    float v0 = a0 * iv + b3[0], v1 = a1 * iv + b3[1], v2 = a2 * iv + b3[2];
    float m = fmaxf(v0, fmaxf(v1, v2));
    float l = logf(__expf(v0 - m) + __expf(v1 - m) + __expf(v2 - m));
    out[n * 3 + 0] = v0 - m - l;
    out[n * 3 + 1] = v1 - m - l;
    out[n * 3 + 2] = v2 - m - l;
}

extern "C" void kernel_launch(void* const* d_in, const int* in_sizes, int n_in,
                              void* d_out, int out_size, void* d_ws, size_t ws_size,
                              hipStream_t stream) {
    (void)n_in; (void)out_size; (void)ws_size;
    const float* x   = (const float*)d_in[0];
    const int*   ei  = (const int*)d_in[1];
    const float* W1  = (const float*)d_in[2];
    const float* as1 = (const float*)d_in[3];
    const float* ad1 = (const float*)d_in[4];
    const float* b1  = (const float*)d_in[5];
    const float* W2  = (const float*)d_in[6];
    const float* as2 = (const float*)d_in[7];
    const float* ad2 = (const float*)d_in[8];
    const float* b2  = (const float*)d_in[9];
    const float* W3  = (const float*)d_in[10];
    const float* as3 = (const float*)d_in[11];
    const float* ad3 = (const float*)d_in[12];
    const float* b3  = (const float*)d_in[13];
    float* out = (float*)d_out;

    const int Nn = in_sizes[0] / 64;   // 10000
    const int E  = in_sizes[1] / 2;    // 160000
    const int ET = E + Nn;
    const int Mp = ((Nn + 127) / 128) * 128;   // 10112

    char* ws = (char*)d_ws;
    size_t off = 0;
    auto alloc = [&](size_t bytes) -> void* {
        void* p = ws + off;
        off = (off + bytes + 255) & ~(size_t)255;
        return p;
    };
    unsigned short* hbuf = (unsigned short*)alloc((size_t)Mp * 1024 * 2);
    void*  big  = alloc((size_t)Mp * 2048 * 2);
    short* A2   = (short*)big;
    float* obuf = (float*)big;
    float* h3   = (float*)alloc((size_t)Nn * 3 * 4);
    short* A1   = (short*)alloc((size_t)Mp * 128 * 2);
    short* B1t  = (short*)alloc((size_t)1024 * 192 * 2);
    short* B2t  = (short*)alloc((size_t)512 * 3072 * 2);
    float* sc   = (float*)alloc((size_t)ET * 8 * 4);
    float* ssrc = (float*)alloc((size_t)Nn * 8 * 4);
    float* sdst = (float*)alloc((size_t)Nn * 8 * 4);
    float* inv  = (float*)alloc((size_t)Nn * 8 * 4);
    int* counts = (int*)alloc((size_t)Nn * 4);
    int* cursor = (int*)alloc((size_t)Nn * 4);
    int* row_off= (int*)alloc((size_t)(Nn + 1) * 4);
    int* colb   = (int*)alloc((size_t)ET * 4);

    hipMemsetAsync(counts, 0, (size_t)Nn * 4, stream);
    hipMemsetAsync(cursor, 0, (size_t)Nn * 4, stream);

    int etb = (ET + 255) / 256;
    k_count<<<etb, 256, 0, stream>>>(ei, E, Nn, counts);
    k_scan<<<1, 256, 0, stream>>>(counts, Nn, ET, row_off);
    k_scatter<<<etb, 256, 0, stream>>>(ei, E, Nn, row_off, cursor, colb);

    k_split_x<<<(Mp * 64 + 255) / 256, 256, 0, stream>>>(x, A1, Nn, Mp, 64);
    k_split_wt<<<dim3(64 / 32, 1024 / 32), 256, 0, stream>>>(W1, B1t, 64, 1024);
    k_split_wt<<<dim3(1024 / 32, 512 / 32), 256, 0, stream>>>(W2, B2t, 1024, 512);

    // ---- layer 1: 64 -> 8x128 concat ----
    {
        int nb = (1024 / 64) * (Mp / 64);
        k_mfma64<<<nb, 256, 0, stream>>>(A1, B1t, hbuf, Nn, 1024, 192, 128, 128, 192);
        int nw = Nn * 8;
        k_scores_bf<8, 128><<<(nw + 3) / 4, 256, 0, stream>>>(hbuf, as1, ad1, ssrc, sdst, Nn);
        k_edge_soft<8><<<(nw + 255) / 256, 256, 0, stream>>>(ssrc, sdst, colb, row_off, sc, inv, Nn);
        k_agg_bf<8, 128, true, true><<<Nn, 256, 0, stream>>>(hbuf, sc, inv, colb, row_off, b1, nullptr, A2);
    }
    // ---- layer 2: 1024 -> 8x64 concat ----
    {
        int nb = (512 / 64) * (Mp / 64);
        k_mfma64<<<nb, 256, 0, stream>>>(A2, B2t, hbuf, Nn, 512, 3072, 2048, 2048, 3072);
        int nw = Nn * 8;
        k_scores_bf<8, 64><<<(nw + 3) / 4, 256, 0, stream>>>(hbuf, as2, ad2, ssrc, sdst, Nn);
        k_edge_soft<8><<<(nw + 255) / 256, 256, 0, stream>>>(ssrc, sdst, colb, row_off, sc, inv, Nn);
        k_agg_bf<8, 64, true, false><<<Nn, 256, 0, stream>>>(hbuf, sc, inv, colb, row_off, b2, obuf, nullptr);
    }
    // ---- layer 3: 512 -> 1x3, mean + log_softmax ----
    {
        k_gemm_n3<<<(Nn + 3) / 4, 256, 0, stream>>>(obuf, W3, h3, Nn, 512);
        k_scores<1, 3><<<(Nn + 3) / 4, 256, 0, stream>>>(h3, as3, ad3, ssrc, sdst, Nn);
        k_edge_soft<1><<<(Nn + 255) / 256, 256, 0, stream>>>(ssrc, sdst, colb, row_off, sc, inv, Nn);
        k_agg3_lsm<<<(Nn + 255) / 256, 256, 0, stream>>>(h3, sc, inv, colb, row_off, b3, out, Nn);
    }
}

// Round 5
// 316.517 us; speedup vs baseline: 1.5414x; 1.0145x over previous
//
#include <hip/hip_runtime.h>
#include <math.h>

#define NEG_SLOPE 0.2f
#define EPS_DEN 1e-16f

typedef __attribute__((ext_vector_type(8))) short bf16x8;
typedef __attribute__((ext_vector_type(4))) float f32x4;

__device__ inline void split2(float a, short& hi, short& lo) {
    unsigned u = __float_as_uint(a);
    unsigned uh = (u + 0x8000u) & 0xFFFF0000u;   // RN to bf16
    float fh = __uint_as_float(uh);
    hi = (short)(uh >> 16);
    float r = a - fh;
    lo = (short)((__float_as_uint(r) + 0x8000u) >> 16);
}

__device__ inline unsigned short f2bf(float f) {   // RNE
    unsigned u = __float_as_uint(f);
    return (unsigned short)((u + 0x7FFFu + ((u >> 16) & 1u)) >> 16);
}
__device__ inline float bflo(unsigned u) { return __uint_as_float(u << 16); }
__device__ inline float bfhi(unsigned u) { return __uint_as_float(u & 0xFFFF0000u); }

// ---------------- CSR build ----------------
__global__ void k_count(const int* __restrict__ ei, int E, int Nn, int* counts) {
    int e = blockIdx.x * blockDim.x + threadIdx.x;
    int ET = E + Nn;
    if (e >= ET) return;
    int d = (e < E) ? ei[E + e] : (e - E);
    atomicAdd(&counts[d], 1);
}

__global__ void k_scan(const int* __restrict__ counts, int Nn, int ET, int* __restrict__ row_off) {
    __shared__ int lds[256];
    int t = threadIdx.x;
    int chunk = (Nn + 255) / 256;
    int b0 = t * chunk, b1 = min(Nn, b0 + chunk);
    int s = 0;
    for (int i = b0; i < b1; i++) s += counts[i];
    lds[t] = s;
    __syncthreads();
    if (t == 0) {
        int run = 0;
        for (int i = 0; i < 256; i++) { int v = lds[i]; lds[i] = run; run += v; }
    }
    __syncthreads();
    int run = lds[t];
    for (int i = b0; i < b1; i++) { row_off[i] = run; run += counts[i]; }
    if (t == 0) row_off[Nn] = ET;
}

__global__ void k_scatter(const int* __restrict__ ei, int E, int Nn,
                          const int* __restrict__ row_off, int* cursor, int* __restrict__ col) {
    int e = blockIdx.x * blockDim.x + threadIdx.x;
    int ET = E + Nn;
    if (e >= ET) return;
    int d = (e < E) ? ei[E + e] : (e - E);
    int s = (e < E) ? ei[e] : (e - E);
    int pos = atomicAdd(&cursor[d], 1);
    col[row_off[d] + pos] = s;
}

// ---------------- split conversions ----------------
__global__ void k_split_x(const float* __restrict__ x, short* __restrict__ A,
                          int M, int Mp, int K) {
    int i = blockIdx.x * blockDim.x + threadIdx.x;
    if (i >= Mp * K) return;
    int row = i / K, c = i - row * K;
    float v = (row < M) ? x[(size_t)row * K + c] : 0.f;
    short hi, lo;
    split2(v, hi, lo);
    A[(size_t)row * (2 * K) + c] = hi;
    A[(size_t)row * (2 * K) + K + c] = lo;
}

__global__ __launch_bounds__(256) void k_split_wt(const float* __restrict__ W,
                                                  short* __restrict__ Bt, int K, int N) {
    __shared__ float s[32][33];
    int k0 = blockIdx.x * 32, n0 = blockIdx.y * 32;
    int tx = threadIdx.x & 31, ty = threadIdx.x >> 5;
    for (int r = ty; r < 32; r += 8) s[r][tx] = W[(size_t)(k0 + r) * N + n0 + tx];
    __syncthreads();
    for (int r = ty; r < 32; r += 8) {
        float v = s[tx][r];
        short hi, lo;
        split2(v, hi, lo);
        size_t base = (size_t)(n0 + r) * (3 * K) + k0 + tx;
        Bt[base] = hi;
        Bt[base + K] = hi;
        Bt[base + 2 * K] = lo;
    }
}

// ---------------- MFMA bf16 GEMM, 64x64 tile, BK=64, double-buffered prefetch ----------------
__global__ __launch_bounds__(256) void k_mfma64(const short* __restrict__ A,
                                                const short* __restrict__ B,
                                                unsigned short* __restrict__ C,
                                                int M, int N, int Ktot, int Kwrap,
                                                int lda, int ldb) {
    __shared__ short As[2][64 * 64];
    __shared__ short Bs[2][64 * 64];
    int t = threadIdx.x;
    int lane = t & 63;
    int wid = t >> 6;

    int nbx = N >> 6;
    int nb = gridDim.x;
    int q = nb >> 3, r = nb & 7;
    int xcd = blockIdx.x & 7, pos = blockIdx.x >> 3;
    int L = (xcd < r ? xcd * (q + 1) : r * (q + 1) + (xcd - r) * q) + pos;
    int bn = (L % nbx) * 64;
    int bm = (L / nbx) * 64;

    int wm = (wid >> 1) * 32, wn = (wid & 1) * 32;
    int fr = lane & 15, kq = lane >> 4;

    f32x4 acc[2][2] = {};
    int nt = Ktot >> 6;
    int cur = 0;

    auto STAGE = [&](int kt, int buf) {
        int k0 = kt << 6;
        int ka = (k0 < Kwrap) ? k0 : k0 - Kwrap;
        #pragma unroll
        for (int qq = 0; qq < 2; qq++) {
            int v = qq * 256 + t;
            int row = v >> 3, slot = v & 7;
            int sko = (slot ^ (row & 7)) << 3;   // pre-swizzled source k-offset
            const short* sa = A + (size_t)(bm + row) * lda + ka + sko;
            const short* sb = B + (size_t)(bn + row) * ldb + k0 + sko;
            short* da = &As[buf][(size_t)(qq * 256 + (wid << 6)) * 8];   // wave-uniform base
            short* db = &Bs[buf][(size_t)(qq * 256 + (wid << 6)) * 8];
            __builtin_amdgcn_global_load_lds((const __attribute__((address_space(1))) void*)sa,
                                             (__attribute__((address_space(3))) void*)da, 16, 0, 0);
            __builtin_amdgcn_global_load_lds((const __attribute__((address_space(1))) void*)sb,
                                             (__attribute__((address_space(3))) void*)db, 16, 0, 0);
        }
    };

    STAGE(0, 0);
    __syncthreads();
    for (int kt = 0; kt < nt; kt++) {
        if (kt + 1 < nt) STAGE(kt + 1, cur ^ 1);
        #pragma unroll
        for (int h = 0; h < 2; h++) {
            bf16x8 af[2], bfv[2];
            #pragma unroll
            for (int i = 0; i < 2; i++) {
                int rowa = wm + i * 16 + fr;
                int rowb = wn + i * 16 + fr;
                int ca = h * 4 + kq;
                af[i]  = *(const bf16x8*)(&As[cur][rowa * 64 + ((ca ^ (rowa & 7)) << 3)]);
                bfv[i] = *(const bf16x8*)(&Bs[cur][rowb * 64 + ((ca ^ (rowb & 7)) << 3)]);
            }
            #pragma unroll
            for (int i = 0; i < 2; i++)
                #pragma unroll
                for (int j = 0; j < 2; j++)
                    acc[i][j] = __builtin_amdgcn_mfma_f32_16x16x32_bf16(af[i], bfv[j], acc[i][j], 0, 0, 0);
        }
        __syncthreads();
        cur ^= 1;
    }
    #pragma unroll
    for (int i = 0; i < 2; i++) {
        int rbase = bm + wm + i * 16 + kq * 4;
        #pragma unroll
        for (int j = 0; j < 2; j++) {
            int colc = bn + wn + j * 16 + fr;
            #pragma unroll
            for (int rg = 0; rg < 4; rg++) {
                int rr = rbase + rg;
                if (rr < M) C[(size_t)rr * N + colc] = f2bf(acc[i][j][rg]);
            }
        }
    }
}

// ---------------- layer-3 GEMM + scores: N=3, K=512, wave per row ----------------
__global__ __launch_bounds__(256) void k_gemm_n3s(const float* __restrict__ A, const float* __restrict__ W,
                                                  const float* __restrict__ as3, const float* __restrict__ ad3,
                                                  float* __restrict__ C3, float* __restrict__ ssrc,
                                                  float* __restrict__ sdst, int M, int K) {
    __shared__ float lw[1536];
    int t = threadIdx.x;
    for (int i = t; i < K * 3; i += 256) lw[i] = W[i];
    __syncthreads();
    int lane = t & 63;
    int n = blockIdx.x * 4 + (t >> 6);
    if (n >= M) return;
    float a0 = 0.f, a1 = 0.f, a2 = 0.f;
    for (int c = lane; c < K; c += 64) {
        float v = A[(size_t)n * K + c];
        a0 += v * lw[c * 3 + 0];
        a1 += v * lw[c * 3 + 1];
        a2 += v * lw[c * 3 + 2];
    }
    #pragma unroll
    for (int off = 32; off > 0; off >>= 1) {
        a0 += __shfl_xor(a0, off);
        a1 += __shfl_xor(a1, off);
        a2 += __shfl_xor(a2, off);
    }
    if (lane == 0) {
        C3[n * 3 + 0] = a0; C3[n * 3 + 1] = a1; C3[n * 3 + 2] = a2;
        ssrc[n] = a0 * as3[0] + a1 * as3[1] + a2 * as3[2];
        sdst[n] = a0 * ad3[0] + a1 * ad3[1] + a2 * ad3[2];
    }
}

// ---------------- scores from bf16 h: wave per (n,h) ----------------
template<int H, int C>
__global__ __launch_bounds__(256) void k_scores_bf(const unsigned short* __restrict__ h,
                                                   const float* __restrict__ a_src,
                                                   const float* __restrict__ a_dst,
                                                   float* __restrict__ ssrc,
                                                   float* __restrict__ sdst, int Nn) {
    int lane = threadIdx.x & 63;
    int w = blockIdx.x * (blockDim.x >> 6) + (threadIdx.x >> 6);
    if (w >= Nn * H) return;
    int n = w / H, hh = w - n * H;
    float as = 0.f, ad = 0.f;
    for (int c = lane; c < C; c += 64) {
        float v = bflo(h[(size_t)n * (H * C) + hh * C + c]);
        as += v * a_src[hh * C + c];
        ad += v * a_dst[hh * C + c];
    }
    #pragma unroll
    for (int off = 32; off > 0; off >>= 1) { as += __shfl_xor(as, off); ad += __shfl_xor(ad, off); }
    if (lane == 0) { ssrc[w] = as; sdst[w] = ad; }
}

// ---------------- segmented softmax: thread per (n,h) ----------------
template<int H>
__global__ void k_edge_soft(const float* __restrict__ ssrc, const float* __restrict__ sdst,
                            const int* __restrict__ col, const int* __restrict__ row_off,
                            float* __restrict__ sc, float* __restrict__ inv, int Nn) {
    int p = blockIdx.x * blockDim.x + threadIdx.x;
    if (p >= Nn * H) return;
    int n = p / H, hh = p - n * H;
    int beg = row_off[n], end = row_off[n + 1];
    float sd = sdst[p];
    float mx = -1e30f;
    for (int j = beg; j < end; j++) {
        float s = ssrc[col[j] * H + hh] + sd;
        s = (s >= 0.f) ? s : NEG_SLOPE * s;
        sc[(size_t)j * H + hh] = s;
        mx = fmaxf(mx, s);
    }
    float den = 0.f;
    for (int j = beg; j < end; j++) {
        float ex = __expf(sc[(size_t)j * H + hh] - mx);
        sc[(size_t)j * H + hh] = ex;
        den += ex;
    }
    inv[p] = 1.f / (den + EPS_DEN);
}

// ---------------- aggregation from bf16 h: block per dst node ----------------
template<int H, int C, bool ELU, bool SPLIT>
__global__ __launch_bounds__(256) void k_agg_bf(const unsigned short* __restrict__ hsrc,
                                                const float* __restrict__ sc,
                                                const float* __restrict__ inv, const int* __restrict__ col,
                                                const int* __restrict__ row_off, const float* __restrict__ bias,
                                                float* __restrict__ out, short* __restrict__ osp) {
    constexpr int D = H * C;
    constexpr int VEC = D / 256;
    int n = blockIdx.x, t = threadIdx.x;
    int head = (VEC * t) / C;
    int beg = row_off[n], end = row_off[n + 1];
    __shared__ int s_col[32];
    __shared__ float s_ex[32 * H];
    float acc[VEC];
    #pragma unroll
    for (int v = 0; v < VEC; v++) acc[v] = 0.f;

    for (int j0 = beg; j0 < end; j0 += 32) {
        int nb = min(32, end - j0);
        __syncthreads();
        if (t < nb) s_col[t] = col[j0 + t];
        if (t < nb * H) s_ex[t] = sc[(size_t)j0 * H + t];
        __syncthreads();
        for (int i = 0; i < nb; i++) {
            const unsigned short* hp = hsrc + (size_t)s_col[i] * D + VEC * t;
            float a = s_ex[i * H + head];
            if (VEC == 4) {
                uint2 u = *(const uint2*)hp;
                acc[0] += a * bflo(u.x);
                acc[1] += a * bfhi(u.x);
                acc[2] += a * bflo(u.y);
                acc[3] += a * bfhi(u.y);
            } else {
                unsigned u = *(const unsigned*)hp;
                acc[0] += a * bflo(u);
                acc[1] += a * bfhi(u);
            }
        }
    }
    float iv = inv[n * H + head];
    #pragma unroll
    for (int v = 0; v < VEC; v++) {
        int idx = VEC * t + v;
        float val = acc[v] * iv + bias[idx];
        if (ELU) val = (val > 0.f) ? val : (__expf(val) - 1.f);
        if (SPLIT) {
            short hi, lo;
            split2(val, hi, lo);
            osp[(size_t)n * (2 * D) + idx] = hi;
            osp[(size_t)n * (2 * D) + D + idx] = lo;
        } else {
            out[(size_t)n * D + idx] = val;
        }
    }
}

// ---------------- fused layer-3: segment softmax + aggregation + log_softmax ----------------
__global__ void k_l3_fused(const float* __restrict__ h3, const float* __restrict__ ssrc,
                           const float* __restrict__ sdst, const int* __restrict__ col,
                           const int* __restrict__ row_off, const float* __restrict__ b3,
                           float* __restrict__ out, int Nn) {
    int n = blockIdx.x * blockDim.x + threadIdx.x;
    if (n >= Nn) return;
    int beg = row_off[n], end = row_off[n + 1];
    float sd = sdst[n];
    float mx = -1e30f;
    for (int j = beg; j < end; j++) {
        float s = ssrc[col[j]] + sd;
        s = (s >= 0.f) ? s : NEG_SLOPE * s;
        mx = fmaxf(mx, s);
    }
    float den = 0.f, a0 = 0.f, a1 = 0.f, a2 = 0.f;
    for (int j = beg; j < end; j++) {
        int sI = col[j];
        float s = ssrc[sI] + sd;
        s = (s >= 0.f) ? s : NEG_SLOPE * s;
        float ex = __expf(s - mx);
        den += ex;
        a0 += ex * h3[sI * 3 + 0];
        a1 += ex * h3[sI * 3 + 1];
        a2 += ex * h3[sI * 3 + 2];
    }
    float iv = 1.f / (den + EPS_DEN);
    float v0 = a0 * iv + b3[0], v1 = a1 * iv + b3[1], v2 = a2 * iv + b3[2];
    float m = fmaxf(v0, fmaxf(v1, v2));
    float l = logf(__expf(v0 - m) + __expf(v1 - m) + __expf(v2 - m));
    out[n * 3 + 0] = v0 - m - l;
    out[n * 3 + 1] = v1 - m - l;
    out[n * 3 + 2] = v2 - m - l;
}

extern "C" void kernel_launch(void* const* d_in, const int* in_sizes, int n_in,
                              void* d_out, int out_size, void* d_ws, size_t ws_size,
                              hipStream_t stream) {
    (void)n_in; (void)out_size; (void)ws_size;
    const float* x   = (const float*)d_in[0];
    const int*   ei  = (const int*)d_in[1];
    const float* W1  = (const float*)d_in[2];
    const float* as1 = (const float*)d_in[3];
    const float* ad1 = (const float*)d_in[4];
    const float* b1  = (const float*)d_in[5];
    const float* W2  = (const float*)d_in[6];
    const float* as2 = (const float*)d_in[7];
    const float* ad2 = (const float*)d_in[8];
    const float* b2  = (const float*)d_in[9];
    const float* W3  = (const float*)d_in[10];
    const float* as3 = (const float*)d_in[11];
    const float* ad3 = (const float*)d_in[12];
    const float* b3  = (const float*)d_in[13];
    float* out = (float*)d_out;

    const int Nn = in_sizes[0] / 64;   // 10000
    const int E  = in_sizes[1] / 2;    // 160000
    const int ET = E + Nn;
    const int Mp = ((Nn + 127) / 128) * 128;   // 10112

    char* ws = (char*)d_ws;
    size_t off = 0;
    auto alloc = [&](size_t bytes) -> void* {
        void* p = ws + off;
        off = (off + bytes + 255) & ~(size_t)255;
        return p;
    };
    unsigned short* hbuf = (unsigned short*)alloc((size_t)Mp * 1024 * 2);
    void*  big  = alloc((size_t)Mp * 2048 * 2);
    short* A2   = (short*)big;
    float* obuf = (float*)big;
    float* h3   = (float*)alloc((size_t)Nn * 3 * 4);
    short* A1   = (short*)alloc((size_t)Mp * 128 * 2);
    short* B1t  = (short*)alloc((size_t)1024 * 192 * 2);
    short* B2t  = (short*)alloc((size_t)512 * 3072 * 2);
    float* sc   = (float*)alloc((size_t)ET * 8 * 4);
    float* ssrc = (float*)alloc((size_t)Nn * 8 * 4);
    float* sdst = (float*)alloc((size_t)Nn * 8 * 4);
    float* inv  = (float*)alloc((size_t)Nn * 8 * 4);
    int* counts = (int*)alloc((size_t)Nn * 2 * 4);   // counts + cursor contiguous
    int* cursor = counts + Nn;
    int* row_off= (int*)alloc((size_t)(Nn + 1) * 4);
    int* colb   = (int*)alloc((size_t)ET * 4);

    hipMemsetAsync(counts, 0, (size_t)Nn * 2 * 4, stream);

    int etb = (ET + 255) / 256;
    k_count<<<etb, 256, 0, stream>>>(ei, E, Nn, counts);
    k_scan<<<1, 256, 0, stream>>>(counts, Nn, ET, row_off);
    k_scatter<<<etb, 256, 0, stream>>>(ei, E, Nn, row_off, cursor, colb);

    k_split_x<<<(Mp * 64 + 255) / 256, 256, 0, stream>>>(x, A1, Nn, Mp, 64);
    k_split_wt<<<dim3(64 / 32, 1024 / 32), 256, 0, stream>>>(W1, B1t, 64, 1024);
    k_split_wt<<<dim3(1024 / 32, 512 / 32), 256, 0, stream>>>(W2, B2t, 1024, 512);

    // ---- layer 1: 64 -> 8x128 concat ----
    {
        int nb = (1024 / 64) * (Mp / 64);
        k_mfma64<<<nb, 256, 0, stream>>>(A1, B1t, hbuf, Nn, 1024, 192, 128, 128, 192);
        int nw = Nn * 8;
        k_scores_bf<8, 128><<<(nw + 3) / 4, 256, 0, stream>>>(hbuf, as1, ad1, ssrc, sdst, Nn);
        k_edge_soft<8><<<(nw + 255) / 256, 256, 0, stream>>>(ssrc, sdst, colb, row_off, sc, inv, Nn);
        k_agg_bf<8, 128, true, true><<<Nn, 256, 0, stream>>>(hbuf, sc, inv, colb, row_off, b1, nullptr, A2);
    }
    // ---- layer 2: 1024 -> 8x64 concat ----
    {
        int nb = (512 / 64) * (Mp / 64);
        k_mfma64<<<nb, 256, 0, stream>>>(A2, B2t, hbuf, Nn, 512, 3072, 2048, 2048, 3072);
        int nw = Nn * 8;
        k_scores_bf<8, 64><<<(nw + 3) / 4, 256, 0, stream>>>(hbuf, as2, ad2, ssrc, sdst, Nn);
        k_edge_soft<8><<<(nw + 255) / 256, 256, 0, stream>>>(ssrc, sdst, colb, row_off, sc, inv, Nn);
        k_agg_bf<8, 64, true, false><<<Nn, 256, 0, stream>>>(hbuf, sc, inv, colb, row_off, b2, obuf, nullptr);
    }
    // ---- layer 3: 512 -> 1x3, mean + log_softmax (fused) ----
    {
        k_gemm_n3s<<<(Nn + 3) / 4, 256, 0, stream>>>(obuf, W3, as3, ad3, h3, ssrc, sdst, Nn, 512);
        k_l3_fused<<<(Nn + 255) / 256, 256, 0, stream>>>(h3, ssrc, sdst, colb, row_off, b3, out, Nn);
    }
}

// Round 6
// 269.330 us; speedup vs baseline: 1.8114x; 1.1752x over previous
//
#include <hip/hip_runtime.h>
#include <math.h>

#define NEG_SLOPE 0.2f
#define EPS_DEN 1e-16f

typedef __attribute__((ext_vector_type(8))) short bf16x8;
typedef __attribute__((ext_vector_type(4))) float f32x4;

__device__ inline void split2(float a, short& hi, short& lo) {
    unsigned u = __float_as_uint(a);
    unsigned uh = (u + 0x8000u) & 0xFFFF0000u;   // RN to bf16
    float fh = __uint_as_float(uh);
    hi = (short)(uh >> 16);
    float r = a - fh;
    lo = (short)((__float_as_uint(r) + 0x8000u) >> 16);
}

__device__ inline unsigned short f2bf(float f) {   // RNE
    unsigned u = __float_as_uint(f);
    return (unsigned short)((u + 0x7FFFu + ((u >> 16) & 1u)) >> 16);
}
__device__ inline float bflo(unsigned u) { return __uint_as_float(u << 16); }
__device__ inline float bfhi(unsigned u) { return __uint_as_float(u & 0xFFFF0000u); }

// ---------------- CSR build ----------------
__global__ void k_count(const int* __restrict__ ei, int E, int Nn, int* counts) {
    int e = blockIdx.x * blockDim.x + threadIdx.x;
    int ET = E + Nn;
    if (e >= ET) return;
    int d = (e < E) ? ei[E + e] : (e - E);
    atomicAdd(&counts[d], 1);
}

__global__ void k_scan(const int* __restrict__ counts, int Nn, int ET, int* __restrict__ row_off) {
    __shared__ int lds[256];
    int t = threadIdx.x;
    int chunk = (Nn + 255) / 256;
    int b0 = t * chunk, b1 = min(Nn, b0 + chunk);
    int s = 0;
    for (int i = b0; i < b1; i++) s += counts[i];
    lds[t] = s;
    __syncthreads();
    if (t == 0) {
        int run = 0;
        for (int i = 0; i < 256; i++) { int v = lds[i]; lds[i] = run; run += v; }
    }
    __syncthreads();
    int run = lds[t];
    for (int i = b0; i < b1; i++) { row_off[i] = run; run += counts[i]; }
    if (t == 0) row_off[Nn] = ET;
}

__global__ void k_scatter(const int* __restrict__ ei, int E, int Nn,
                          const int* __restrict__ row_off, int* cursor, int* __restrict__ col) {
    int e = blockIdx.x * blockDim.x + threadIdx.x;
    int ET = E + Nn;
    if (e >= ET) return;
    int d = (e < E) ? ei[E + e] : (e - E);
    int s = (e < E) ? ei[e] : (e - E);
    int pos = atomicAdd(&cursor[d], 1);
    col[row_off[d] + pos] = s;
}

// ---------------- split conversions ----------------
__global__ void k_split_x(const float* __restrict__ x, short* __restrict__ A,
                          int M, int Mp, int K) {
    int i = blockIdx.x * blockDim.x + threadIdx.x;
    if (i >= Mp * K) return;
    int row = i / K, c = i - row * K;
    float v = (row < M) ? x[(size_t)row * K + c] : 0.f;
    short hi, lo;
    split2(v, hi, lo);
    A[(size_t)row * (2 * K) + c] = hi;
    A[(size_t)row * (2 * K) + K + c] = lo;
}

// W [K,N] f32 -> Bt [N, 2K] bf16: Bt[n][k]=hi, Bt[n][K+k]=hi  (2-term: err = A.Blo ~ 2^-9)
__global__ __launch_bounds__(256) void k_split_wt(const float* __restrict__ W,
                                                  short* __restrict__ Bt, int K, int N) {
    __shared__ float s[32][33];
    int k0 = blockIdx.x * 32, n0 = blockIdx.y * 32;
    int tx = threadIdx.x & 31, ty = threadIdx.x >> 5;
    for (int r = ty; r < 32; r += 8) s[r][tx] = W[(size_t)(k0 + r) * N + n0 + tx];
    __syncthreads();
    for (int r = ty; r < 32; r += 8) {
        float v = s[tx][r];
        unsigned u = __float_as_uint(v);
        short hi = (short)((u + 0x7FFFu + ((u >> 16) & 1u)) >> 16);   // RNE
        size_t base = (size_t)(n0 + r) * (2 * K) + k0 + tx;
        Bt[base] = hi;
        Bt[base + K] = hi;
    }
}

// ---------------- MFMA bf16 GEMM, 64x64 tile, BK=32, XCD-grouped, swizzled LDS ----------------
__global__ __launch_bounds__(256) void k_mfma64(const short* __restrict__ A,
                                                const short* __restrict__ B,
                                                unsigned short* __restrict__ C,
                                                int M, int N, int Ktot,
                                                int lda, int ldb) {
    __shared__ short As[64 * 32];
    __shared__ short Bs[64 * 32];
    int t = threadIdx.x;
    int lane = t & 63;
    int wid = t >> 6;

    int nbx = N >> 6;
    int nb = gridDim.x;
    int q = nb >> 3, r = nb & 7;
    int xcd = blockIdx.x & 7, pos = blockIdx.x >> 3;
    int L = (xcd < r ? xcd * (q + 1) : r * (q + 1) + (xcd - r) * q) + pos;
    int bn = (L % nbx) * 64;
    int bm = (L / nbx) * 64;

    int wm = (wid >> 1) * 32, wn = (wid & 1) * 32;
    int fr = lane & 15, kq = lane >> 4;

    // staging: thread t covers row = t>>2, slot = t&3 (8 shorts), pre-swizzled source
    int srow = t >> 2, sslot = t & 3;
    int sko = ((sslot ^ ((srow >> 1) & 3)) << 3);

    f32x4 acc[2][2] = {};

    for (int k0 = 0; k0 < Ktot; k0 += 32) {
        {
            const short* sa = A + (size_t)(bm + srow) * lda + k0 + sko;
            const short* sb = B + (size_t)(bn + srow) * ldb + k0 + sko;
            short* da = As + (size_t)(wid << 6) * 8;   // wave-uniform base, lane*16B auto
            short* db = Bs + (size_t)(wid << 6) * 8;
            __builtin_amdgcn_global_load_lds((const __attribute__((address_space(1))) void*)sa,
                                             (__attribute__((address_space(3))) void*)da, 16, 0, 0);
            __builtin_amdgcn_global_load_lds((const __attribute__((address_space(1))) void*)sb,
                                             (__attribute__((address_space(3))) void*)db, 16, 0, 0);
        }
        __syncthreads();
        bf16x8 af[2], bfv[2];
        #pragma unroll
        for (int i = 0; i < 2; i++) {
            int rowa = wm + i * 16 + fr;
            int rowb = wn + i * 16 + fr;
            af[i]  = *(const bf16x8*)(As + rowa * 32 + ((kq ^ ((rowa >> 1) & 3)) << 3));
            bfv[i] = *(const bf16x8*)(Bs + rowb * 32 + ((kq ^ ((rowb >> 1) & 3)) << 3));
        }
        #pragma unroll
        for (int i = 0; i < 2; i++)
            #pragma unroll
            for (int j = 0; j < 2; j++)
                acc[i][j] = __builtin_amdgcn_mfma_f32_16x16x32_bf16(af[i], bfv[j], acc[i][j], 0, 0, 0);
        __syncthreads();
    }
    #pragma unroll
    for (int i = 0; i < 2; i++) {
        int rbase = bm + wm + i * 16 + kq * 4;
        #pragma unroll
        for (int j = 0; j < 2; j++) {
            int colc = bn + wn + j * 16 + fr;
            #pragma unroll
            for (int rg = 0; rg < 4; rg++) {
                int rr = rbase + rg;
                if (rr < M) C[(size_t)rr * N + colc] = f2bf(acc[i][j][rg]);
            }
        }
    }
}

// ---------------- layer-3 GEMM + scores: N=3, K=512, wave per row ----------------
__global__ __launch_bounds__(256) void k_gemm_n3s(const float* __restrict__ A, const float* __restrict__ W,
                                                  const float* __restrict__ as3, const float* __restrict__ ad3,
                                                  float* __restrict__ C3, float* __restrict__ ssrc,
                                                  float* __restrict__ sdst, int M, int K) {
    __shared__ float lw[1536];
    int t = threadIdx.x;
    for (int i = t; i < K * 3; i += 256) lw[i] = W[i];
    __syncthreads();
    int lane = t & 63;
    int n = blockIdx.x * 4 + (t >> 6);
    if (n >= M) return;
    float a0 = 0.f, a1 = 0.f, a2 = 0.f;
    for (int c = lane; c < K; c += 64) {
        float v = A[(size_t)n * K + c];
        a0 += v * lw[c * 3 + 0];
        a1 += v * lw[c * 3 + 1];
        a2 += v * lw[c * 3 + 2];
    }
    #pragma unroll
    for (int off = 32; off > 0; off >>= 1) {
        a0 += __shfl_xor(a0, off);
        a1 += __shfl_xor(a1, off);
        a2 += __shfl_xor(a2, off);
    }
    if (lane == 0) {
        C3[n * 3 + 0] = a0; C3[n * 3 + 1] = a1; C3[n * 3 + 2] = a2;
        ssrc[n] = a0 * as3[0] + a1 * as3[1] + a2 * as3[2];
        sdst[n] = a0 * ad3[0] + a1 * ad3[1] + a2 * ad3[2];
    }
}

// ---------------- scores from bf16 h: wave per (n,h) ----------------
template<int H, int C>
__global__ __launch_bounds__(256) void k_scores_bf(const unsigned short* __restrict__ h,
                                                   const float* __restrict__ a_src,
                                                   const float* __restrict__ a_dst,
                                                   float* __restrict__ ssrc,
                                                   float* __restrict__ sdst, int Nn) {
    int lane = threadIdx.x & 63;
    int w = blockIdx.x * (blockDim.x >> 6) + (threadIdx.x >> 6);
    if (w >= Nn * H) return;
    int n = w / H, hh = w - n * H;
    float as = 0.f, ad = 0.f;
    for (int c0 = lane * 2; c0 < C; c0 += 128) {
        unsigned u = *(const unsigned*)(h + (size_t)n * (H * C) + hh * C + c0);
        float v0 = bflo(u), v1 = bfhi(u);
        as += v0 * a_src[hh * C + c0] + v1 * a_src[hh * C + c0 + 1];
        ad += v0 * a_dst[hh * C + c0] + v1 * a_dst[hh * C + c0 + 1];
    }
    #pragma unroll
    for (int off = 32; off > 0; off >>= 1) { as += __shfl_xor(as, off); ad += __shfl_xor(ad, off); }
    if (lane == 0) { ssrc[w] = as; sdst[w] = ad; }
}

// ---------------- segmented softmax stats only: thread per (n,h) -> mx, inv ----------------
template<int H>
__global__ void k_edge_soft(const float* __restrict__ ssrc, const float* __restrict__ sdst,
                            const int* __restrict__ col, const int* __restrict__ row_off,
                            float* __restrict__ mxp, float* __restrict__ inv, int Nn) {
    int p = blockIdx.x * blockDim.x + threadIdx.x;
    if (p >= Nn * H) return;
    int n = p / H, hh = p - n * H;
    int beg = row_off[n], end = row_off[n + 1];
    float sd = sdst[p];
    float mx = -1e30f;
    for (int j = beg; j < end; j++) {
        float s = ssrc[col[j] * H + hh] + sd;
        s = (s >= 0.f) ? s : NEG_SLOPE * s;
        mx = fmaxf(mx, s);
    }
    float den = 0.f;
    for (int j = beg; j < end; j++) {
        float s = ssrc[col[j] * H + hh] + sd;
        s = (s >= 0.f) ? s : NEG_SLOPE * s;
        den += __expf(s - mx);
    }
    mxp[p] = mx;
    inv[p] = 1.f / (den + EPS_DEN);
}

// ---------------- aggregation from bf16 h, alpha recomputed inline ----------------
template<int H, int C, bool ELU, bool SPLIT>
__global__ __launch_bounds__(256) void k_agg_bf(const unsigned short* __restrict__ hsrc,
                                                const float* __restrict__ ssrc,
                                                const float* __restrict__ sdst,
                                                const float* __restrict__ mxp,
                                                const float* __restrict__ inv,
                                                const int* __restrict__ col,
                                                const int* __restrict__ row_off,
                                                const float* __restrict__ bias,
                                                float* __restrict__ out, short* __restrict__ osp) {
    constexpr int D = H * C;
    constexpr int VEC = D / 256;
    int n = blockIdx.x, t = threadIdx.x;
    int head = (VEC * t) / C;
    int beg = row_off[n], end = row_off[n + 1];
    __shared__ int s_col[32];
    __shared__ float s_ex[32 * H];
    __shared__ float sh_mx[H], sh_sd[H];
    if (t < H) { sh_mx[t] = mxp[n * H + t]; sh_sd[t] = sdst[n * H + t]; }
    float acc[VEC];
    #pragma unroll
    for (int v = 0; v < VEC; v++) acc[v] = 0.f;

    for (int j0 = beg; j0 < end; j0 += 32) {
        int nb = min(32, end - j0);
        __syncthreads();
        if (t < nb) s_col[t] = col[j0 + t];
        if (t < nb * H) {
            int e = t >> 3, hh = t & 7;
            int cj = col[j0 + e];
            float s = ssrc[cj * H + hh] + sh_sd[hh];
            s = (s >= 0.f) ? s : NEG_SLOPE * s;
            s_ex[t] = __expf(s - sh_mx[hh]);
        }
        __syncthreads();
        for (int i = 0; i < nb; i++) {
            const unsigned short* hp = hsrc + (size_t)s_col[i] * D + VEC * t;
            float a = s_ex[i * H + head];
            if (VEC == 4) {
                uint2 u = *(const uint2*)hp;
                acc[0] += a * bflo(u.x);
                acc[1] += a * bfhi(u.x);
                acc[2] += a * bflo(u.y);
                acc[3] += a * bfhi(u.y);
            } else {
                unsigned u = *(const unsigned*)hp;
                acc[0] += a * bflo(u);
                acc[1] += a * bfhi(u);
            }
        }
    }
    float iv = inv[n * H + head];
    #pragma unroll
    for (int v = 0; v < VEC; v++) {
        int idx = VEC * t + v;
        float val = acc[v] * iv + bias[idx];
        if (ELU) val = (val > 0.f) ? val : (__expf(val) - 1.f);
        if (SPLIT) {
            short hi, lo;
            split2(val, hi, lo);
            osp[(size_t)n * (2 * D) + idx] = hi;
            osp[(size_t)n * (2 * D) + D + idx] = lo;
        } else {
            out[(size_t)n * D + idx] = val;
        }
    }
}

// ---------------- fused layer-3: segment softmax + aggregation + log_softmax ----------------
__global__ void k_l3_fused(const float* __restrict__ h3, const float* __restrict__ ssrc,
                           const float* __restrict__ sdst, const int* __restrict__ col,
                           const int* __restrict__ row_off, const float* __restrict__ b3,
                           float* __restrict__ out, int Nn) {
    int n = blockIdx.x * blockDim.x + threadIdx.x;
    if (n >= Nn) return;
    int beg = row_off[n], end = row_off[n + 1];
    float sd = sdst[n];
    float mx = -1e30f;
    for (int j = beg; j < end; j++) {
        float s = ssrc[col[j]] + sd;
        s = (s >= 0.f) ? s : NEG_SLOPE * s;
        mx = fmaxf(mx, s);
    }
    float den = 0.f, a0 = 0.f, a1 = 0.f, a2 = 0.f;
    for (int j = beg; j < end; j++) {
        int sI = col[j];
        float s = ssrc[sI] + sd;
        s = (s >= 0.f) ? s : NEG_SLOPE * s;
        float ex = __expf(s - mx);
        den += ex;
        a0 += ex * h3[sI * 3 + 0];
        a1 += ex * h3[sI * 3 + 1];
        a2 += ex * h3[sI * 3 + 2];
    }
    float iv = 1.f / (den + EPS_DEN);
    float v0 = a0 * iv + b3[0], v1 = a1 * iv + b3[1], v2 = a2 * iv + b3[2];
    float m = fmaxf(v0, fmaxf(v1, v2));
    float l = logf(__expf(v0 - m) + __expf(v1 - m) + __expf(v2 - m));
    out[n * 3 + 0] = v0 - m - l;
    out[n * 3 + 1] = v1 - m - l;
    out[n * 3 + 2] = v2 - m - l;
}

extern "C" void kernel_launch(void* const* d_in, const int* in_sizes, int n_in,
                              void* d_out, int out_size, void* d_ws, size_t ws_size,
                              hipStream_t stream) {
    (void)n_in; (void)out_size; (void)ws_size;
    const float* x   = (const float*)d_in[0];
    const int*   ei  = (const int*)d_in[1];
    const float* W1  = (const float*)d_in[2];
    const float* as1 = (const float*)d_in[3];
    const float* ad1 = (const float*)d_in[4];
    const float* b1  = (const float*)d_in[5];
    const float* W2  = (const float*)d_in[6];
    const float* as2 = (const float*)d_in[7];
    const float* ad2 = (const float*)d_in[8];
    const float* b2  = (const float*)d_in[9];
    const float* W3  = (const float*)d_in[10];
    const float* as3 = (const float*)d_in[11];
    const float* ad3 = (const float*)d_in[12];
    const float* b3  = (const float*)d_in[13];
    float* out = (float*)d_out;

    const int Nn = in_sizes[0] / 64;   // 10000
    const int E  = in_sizes[1] / 2;    // 160000
    const int ET = E + Nn;
    const int Mp = ((Nn + 127) / 128) * 128;   // 10112

    char* ws = (char*)d_ws;
    size_t off = 0;
    auto alloc = [&](size_t bytes) -> void* {
        void* p = ws + off;
        off = (off + bytes + 255) & ~(size_t)255;
        return p;
    };
    unsigned short* hbuf = (unsigned short*)alloc((size_t)Mp * 1024 * 2);
    void*  big  = alloc((size_t)Mp * 2048 * 2);
    short* A2   = (short*)big;
    float* obuf = (float*)big;
    float* h3   = (float*)alloc((size_t)Nn * 3 * 4);
    short* A1   = (short*)alloc((size_t)Mp * 128 * 2);
    short* B1t  = (short*)alloc((size_t)1024 * 128 * 2);
    short* B2t  = (short*)alloc((size_t)512 * 2048 * 2);
    float* mxp  = (float*)alloc((size_t)Nn * 8 * 4);
    float* ssrc = (float*)alloc((size_t)Nn * 8 * 4);
    float* sdst = (float*)alloc((size_t)Nn * 8 * 4);
    float* inv  = (float*)alloc((size_t)Nn * 8 * 4);
    int* counts = (int*)alloc((size_t)Nn * 2 * 4);   // counts + cursor contiguous
    int* cursor = counts + Nn;
    int* row_off= (int*)alloc((size_t)(Nn + 1) * 4);
    int* colb   = (int*)alloc((size_t)ET * 4);

    hipMemsetAsync(counts, 0, (size_t)Nn * 2 * 4, stream);

    int etb = (ET + 255) / 256;
    k_count<<<etb, 256, 0, stream>>>(ei, E, Nn, counts);
    k_scan<<<1, 256, 0, stream>>>(counts, Nn, ET, row_off);
    k_scatter<<<etb, 256, 0, stream>>>(ei, E, Nn, row_off, cursor, colb);

    k_split_x<<<(Mp * 64 + 255) / 256, 256, 0, stream>>>(x, A1, Nn, Mp, 64);
    k_split_wt<<<dim3(64 / 32, 1024 / 32), 256, 0, stream>>>(W1, B1t, 64, 1024);
    k_split_wt<<<dim3(1024 / 32, 512 / 32), 256, 0, stream>>>(W2, B2t, 1024, 512);

    // ---- layer 1: 64 -> 8x128 concat ----
    {
        int nb = (1024 / 64) * (Mp / 64);
        k_mfma64<<<nb, 256, 0, stream>>>(A1, B1t, hbuf, Nn, 1024, 128, 128, 128);
        int nw = Nn * 8;
        k_scores_bf<8, 128><<<(nw + 3) / 4, 256, 0, stream>>>(hbuf, as1, ad1, ssrc, sdst, Nn);
        k_edge_soft<8><<<(nw + 255) / 256, 256, 0, stream>>>(ssrc, sdst, colb, row_off, mxp, inv, Nn);
        k_agg_bf<8, 128, true, true><<<Nn, 256, 0, stream>>>(hbuf, ssrc, sdst, mxp, inv, colb, row_off, b1, nullptr, A2);
    }
    // ---- layer 2: 1024 -> 8x64 concat ----
    {
        int nb = (512 / 64) * (Mp / 64);
        k_mfma64<<<nb, 256, 0, stream>>>(A2, B2t, hbuf, Nn, 512, 2048, 2048, 2048);
        int nw = Nn * 8;
        k_scores_bf<8, 64><<<(nw + 3) / 4, 256, 0, stream>>>(hbuf, as2, ad2, ssrc, sdst, Nn);
        k_edge_soft<8><<<(nw + 255) / 256, 256, 0, stream>>>(ssrc, sdst, colb, row_off, mxp, inv, Nn);
        k_agg_bf<8, 64, true, false><<<Nn, 256, 0, stream>>>(hbuf, ssrc, sdst, mxp, inv, colb, row_off, b2, obuf, nullptr);
    }
    // ---- layer 3: 512 -> 1x3, mean + log_softmax (fused) ----
    {
        k_gemm_n3s<<<(Nn + 3) / 4, 256, 0, stream>>>(obuf, W3, as3, ad3, h3, ssrc, sdst, Nn, 512);
        k_l3_fused<<<(Nn + 255) / 256, 256, 0, stream>>>(h3, ssrc, sdst, colb, row_off, b3, out, Nn);
    }
}